// Round 2
// 211.662 us; speedup vs baseline: 1.0167x; 1.0167x over previous
//
#include <hip/hip_runtime.h>
#include <hip/hip_bf16.h>
#include <string.h>

// MultiHeadAttention: B=1, L=4096, D=1024, H=16, HD=64, causal.
// R14: R13 failed because Vt is stored KEY-PERMUTED (pos = rotl2(token) within
// each 64-token window, from gemm_qkv's packed epilogue) while R13 built P in
// true-key order. R12 was consistent (its P-LDS store applied the same rotl2).
// R14 works in position space throughout:
//  - swapped QK^T (S^T = K*Q^T) with K rows fed through rotr2(pos) so the
//    score fragment is indexed by POSITION; causal mask uses the true token.
//  - PV via v_mfma_f32_16x16x16_bf16: its B-fragment (k=quad*4+j, col=l16)
//    EXACTLY matches the S^T output layout -> exp2+cvt_pk feed PV in-situ.
//    No P LDS, no cross-lane ops. V read at natural stored positions (b64).
//  - row sums in f32 VALU + 2 shfl_xor (permutation-invariant).
//  - 16 waves = 4 q-subs(32 rows) x 4 key-quarters(32 keys): 4 waves/SIMD,
//    K/V LDS reads per round ~2.4x lower than R12. 4-way merge through Ml
//    union (107.5KB LDS, 1 block/CU).

typedef unsigned short ushort_t;
typedef __attribute__((ext_vector_type(8))) short short8;
typedef __attribute__((ext_vector_type(4))) short short4_t;
typedef __attribute__((ext_vector_type(4))) float f32x4;

#define MFMA16(a, b, c) __builtin_amdgcn_mfma_f32_16x16x32_bf16(a, b, c, 0, 0, 0)

#if __has_builtin(__builtin_amdgcn_mfma_f32_16x16x16bf16_1k)
#define HAVE_MFMA16K 1
__device__ __forceinline__ f32x4 mfma16x16(short4_t a, short4_t b, f32x4 c) {
    return __builtin_amdgcn_mfma_f32_16x16x16bf16_1k(a, b, c, 0, 0, 0);
}
#else
#define HAVE_MFMA16K 0
__device__ __forceinline__ f32x4 mfma16x16(short4_t a, short4_t b, f32x4 c) {
    asm("s_nop 1\n\tv_mfma_f32_16x16x16_bf16 %0, %1, %2, %0"
        : "+v"(c) : "v"(a), "v"(b));
    return c;
}
#endif

static constexpr int Lq = 4096;
static constexpr int Dm = 1024;
static constexpr int NH = 16;
static constexpr int HD = 64;
static constexpr int D3 = 3072;
static constexpr float SCALE_LOG2E = 0.125f * 1.44269504088896340736f;

__device__ __forceinline__ ushort_t f2bf(float f) {
    union { float f; unsigned int u; } x{f};
    unsigned int u = x.u;
    u += 0x7fffu + ((u >> 16) & 1u);   // RNE
    return (ushort_t)(u >> 16);
}

// packed fp32x2 -> bf16x2 (compiler emits v_cvt_pk_bf16_f32), RNE
__device__ __forceinline__ unsigned int cvtpk(float a, float b) {
    __hip_bfloat162 h = __float22bfloat162_rn(make_float2(a, b));
    unsigned int u;
    memcpy(&u, &h, 4);
    return u;
}

__device__ __forceinline__ void gl2lds16(const ushort_t* g, ushort_t* l) {
    __builtin_amdgcn_global_load_lds(
        (const __attribute__((address_space(1))) unsigned int*)g,
        (__attribute__((address_space(3))) unsigned int*)l, 16, 0, 0);
}

// ---------------- prep: cvt X->bf16 + transpose-convert both W ----------------
__global__ void __launch_bounds__(256)
prep(const float* __restrict__ X, const float* __restrict__ Wqkv,
     const float* __restrict__ Wproj, ushort_t* __restrict__ Xb,
     ushort_t* __restrict__ WqkvT, ushort_t* __restrict__ WprojT) {
    __shared__ float tile[32][33];
    const int bid = blockIdx.x, tid = threadIdx.x;
    if (bid < 4096) {
        int i = (bid * 256 + tid) * 4;
        float4 v = *(const float4*)&X[i];
        ushort_t r[4] = { f2bf(v.x), f2bf(v.y), f2bf(v.z), f2bf(v.w) };
        *(uint2*)&Xb[i] = *(uint2*)r;
        return;
    }
    const float* W; ushort_t* Wt; int Nd, nb, kb;
    if (bid < 7168) {
        int b = bid - 4096; W = Wqkv;  Wt = WqkvT;  Nd = 3072;
        nb = (b % 96) * 32; kb = (b / 96) * 32;
    } else {
        int b = bid - 7168; W = Wproj; Wt = WprojT; Nd = 1024;
        nb = (b % 32) * 32; kb = (b / 32) * 32;
    }
    const int tx = tid & 31, ty = tid >> 5;
    for (int j = 0; j < 32; j += 8)
        tile[ty + j][tx] = W[(size_t)(kb + ty + j) * Nd + nb + tx];
    __syncthreads();
    for (int j = 0; j < 32; j += 8)
        Wt[(size_t)(nb + ty + j) * Dm + kb + tx] = f2bf(tile[tx][ty + j]);
}

// ---------------- QKV GEMM with fused V-transpose epilogue ----------------
// cols [0,1024): *SCALE_LOG2E -> qkvB (Q); [1024,2048): -> qkvB (K);
// [2048,3072): transposed+key-permuted (pos = rotl2(token) per 64-window) to
// Vt via packed b128 stores.
__global__ void __launch_bounds__(256)
gemm_qkv(const ushort_t* __restrict__ A, const ushort_t* __restrict__ Bt,
         const float* __restrict__ bias, ushort_t* __restrict__ Cq,
         ushort_t* __restrict__ Vt) {
    __shared__ alignas(16) ushort_t Alds[128 * 32];
    __shared__ alignas(16) ushort_t Blds[128 * 32];
    const int tid  = threadIdx.x;
    const int lane = tid & 63;
    const int w    = tid >> 6;
    const int quad = lane >> 4;
    const int l16  = lane & 15;
    const int mbase = blockIdx.x * 128;
    const int nbase = blockIdx.y * 128;
    const int moff  = (w >> 1) * 64;
    const int noff  = (w & 1) * 64;
    const int K = Dm;

    f32x4 acc[4][4] = {};

    for (int kb = 0; kb < K; kb += 32) {
        __syncthreads();
        #pragma unroll
        for (int c = 0; c < 2; c++) {
            int id  = w * 128 + c * 64 + lane;
            int row = id >> 2, col = (id & 3) * 8;
            gl2lds16(&A[(size_t)(mbase + row) * K + kb + col], &Alds[(size_t)(w * 128 + c * 64) * 8]);
            gl2lds16(&Bt[(size_t)(nbase + row) * K + kb + col], &Blds[(size_t)(w * 128 + c * 64) * 8]);
        }
        __syncthreads();
        short8 a[4], b[4];
        #pragma unroll
        for (int m = 0; m < 4; m++)
            a[m] = *(const short8*)&Alds[(moff + m * 16 + l16) * 32 + quad * 8];
        #pragma unroll
        for (int n = 0; n < 4; n++)
            b[n] = *(const short8*)&Blds[(noff + n * 16 + l16) * 32 + quad * 8];
        #pragma unroll
        for (int m = 0; m < 4; m++)
            #pragma unroll
            for (int n = 0; n < 4; n++)
                acc[m][n] = MFMA16(a[m], b[n], acc[m][n]);
    }

    if (nbase < 2048) {
        const bool qscale = (nbase < 1024);
        #pragma unroll
        for (int m = 0; m < 4; m++)
            #pragma unroll
            for (int n = 0; n < 4; n++)
                #pragma unroll
                for (int r = 0; r < 4; r++) {
                    int row = mbase + moff + m * 16 + quad * 4 + r;
                    int col = nbase + noff + n * 16 + l16;
                    float v = acc[m][n][r] + bias[col];
                    if (qscale) v *= SCALE_LOG2E;
                    Cq[(size_t)row * D3 + col] = f2bf(v);
                }
    } else {
        // V block: token64 = m*16 + quad*4 + r -> pos = (quad*4+r)*4 + m.
        // For fixed (quad, r-pair): m-registers give 8 consecutive positions.
        const int dbase = nbase - 2048 + noff;
        const size_t kb0 = (size_t)mbase + moff;   // 64-aligned key window
        #pragma unroll
        for (int n = 0; n < 4; n++) {
            const float bv = bias[nbase + noff + n * 16 + l16];
            ushort_t* vrow = Vt + (size_t)(dbase + n * 16 + l16) * Lq + kb0 + quad * 16;
            #pragma unroll
            for (int rp = 0; rp < 2; rp++) {
                ushort_t pk[8];
                #pragma unroll
                for (int dr = 0; dr < 2; dr++)
                    #pragma unroll
                    for (int m = 0; m < 4; m++)
                        pk[dr * 4 + m] = f2bf(acc[m][n][2 * rp + dr] + bv);
                *(short8*)(vrow + rp * 8) = *(const short8*)pk;
            }
        }
    }
}

// ---------------- flash attention (R14) ----------------
// grid 256 = 16 pairs x 16 heads; head = bid & 15 (XCD pin); p = bid >> 4.
// block 1024 = 16 waves: sub = w&3 (32 q-rows), qtr = w>>2 (32 key-positions).
// sel 0: chunk p; sel 1: chunk 31-p => 33 rounds/block, uniform.
// Position space: Vt stores pos = rotl2(token) per 64-window; K rows are fed
// through token = rotr2(pos) so S^T is position-indexed; mask by true token.
// PV consumes exp2'd scores in-register via 16x16x16 MFMA (B-frag == S^T
// layout). 4-way merge (o, sacc) through Ml union region.
__global__ void __launch_bounds__(1024)
attn_fwd(const ushort_t* __restrict__ qkv, const ushort_t* __restrict__ Vt,
         ushort_t* __restrict__ O) {
    union SMem {
        struct { ushort_t K[2][2][64 * 64]; ushort_t V[2][2][64 * 64]; } kv;
        float Ml[3 * 256 * 35];             // 34 floats/thread, pitch 35
    };
    __shared__ SMem sm;

    const int tid  = threadIdx.x;
    const int lane = tid & 63;
    const int w    = tid >> 6;          // [0,16)
    const int qtr  = w >> 2;            // key quarter [0,4)
    const int sub  = w & 3;             // q sub-chunk (32 rows)
    const int quad = lane >> 4;
    const int l16  = lane & 15;
    const int bid  = blockIdx.x;
    const int h    = bid & 15;
    const int p    = bid >> 4;          // [0,16)
    const float NEG_INF = -__builtin_inff();

    const ushort_t* kbase = qkv + Dm + h * HD;           // K rows, stride D3
    const ushort_t* vbase = Vt + (size_t)h * HD * Lq;    // V^T rows, stride Lq

    // K fragment offsets: A-row i <-> pos = (qtr&1)*32 + s*16 + i, LDS row =
    // token = rotr2(pos) = (i&3)*16 + (qtr&1)*8 + s*4 + (i>>2), i = l16.
    // K staging swizzle f(tok) = ((tok>>4)&3)*2 + (tok&1) spreads the 16
    // fragment rows over all 8 column groups (conflict-free b128).
    int koff[2][2];
    #pragma unroll
    for (int s = 0; s < 2; s++) {
        const int tok = (l16 & 3) * 16 + (qtr & 1) * 8 + s * 4 + (l16 >> 2);
        const int fk  = ((l16 & 3) << 1) | ((l16 >> 2) & 1);
        #pragma unroll
        for (int kh = 0; kh < 2; kh++)
            koff[s][kh] = tok * 64 + (((kh * 4 + quad) ^ fk) * 8);
    }
    // V fragment offsets: natural stored positions, rows = d.
    int voff[4][2];
    #pragma unroll
    for (int t4 = 0; t4 < 4; t4++)
        #pragma unroll
        for (int s = 0; s < 2; s++) {
            const int row = t4 * 16 + l16;
            const int g = (qtr & 1) * 4 + s * 2 + (quad >> 1);
            voff[t4][s] = row * 64 + ((g ^ (l16 & 7)) * 8) + (quad & 1) * 4;
        }
    // true token of st[.][s][r4] within round: r*128 + kmc + s*4 + r4*16
    const int kmc = (qtr >> 1) * 64 + (qtr & 1) * 8 + quad;

    // staging: waves 0-7 stage K (both 64-tiles), waves 8-15 stage V.
    const int  tv  = tid & 511;
    const int  rr  = tv >> 3;
    const int  ccK = (tv & 7) ^ ((((rr >> 4) & 3) << 1) | (rr & 1));
    const int  ccV = (tv & 7) ^ (rr & 7);
    const bool isK = (tid < 512);
    const int  dsto = (w & 7) * 512;
    const ushort_t* kse = kbase + (size_t)rr * D3 + ccK * 8;
    const ushort_t* vse = vbase + (size_t)rr * Lq + ccV * 8;

    for (int sel = 0; sel < 2; sel++) {
        const int c      = sel ? (31 - p) : p;
        const int qc     = c * 128;
        const int rounds = c + 1;
        const int qrow0  = qc + sub * 32;

        short8 qf[2][2];
        #pragma unroll
        for (int m = 0; m < 2; m++) {
            const ushort_t* qr = qkv + (size_t)(qrow0 + m * 16 + l16) * D3 + h * HD;
            qf[m][0] = *(const short8*)(qr + quad * 8);
            qf[m][1] = *(const short8*)(qr + 32 + quad * 8);
        }

        f32x4 o[2][4] = {};
        float sacc[2] = { 0.f, 0.f };

        const ushort_t* kp = kse;
        const ushort_t* vp = vse;

        auto stage = [&](int b) {
            if (isK) {
                gl2lds16(kp,           &sm.kv.K[0][b][dsto]);
                gl2lds16(kp + 64 * D3, &sm.kv.K[1][b][dsto]);
            } else {
                gl2lds16(vp,           &sm.kv.V[0][b][dsto]);
                gl2lds16(vp + 64,      &sm.kv.V[1][b][dsto]);
            }
            kp += (size_t)128 * D3;
            vp += 128;
        };

        stage(0);

        for (int r = 0; r < rounds; r++) {
            const int buf = r & 1;
            __syncthreads();
            if (r + 1 < rounds) stage(buf ^ 1);

            const ushort_t* Kb = &sm.kv.K[qtr >> 1][buf][0];
            const ushort_t* Vb = &sm.kv.V[qtr >> 1][buf][0];
            const bool domask = (r == rounds - 1);

            short8 kf[2][2];
            #pragma unroll
            for (int s = 0; s < 2; s++)
                #pragma unroll
                for (int kh = 0; kh < 2; kh++)
                    kf[s][kh] = *(const short8*)&Kb[koff[s][kh]];

            // S^T = K * Q^T (position-indexed rows); exp2 + pack in-register.
            short4_t pT[2][2];
            #pragma unroll
            for (int m = 0; m < 2; m++) {
                const int qg = qrow0 + m * 16 + l16;
                #pragma unroll
                for (int s = 0; s < 2; s++) {
                    f32x4 t = {};
                    t = MFMA16(kf[s][0], qf[m][0], t);
                    t = MFMA16(kf[s][1], qf[m][1], t);
                    float e[4];
                    #pragma unroll
                    for (int r4 = 0; r4 < 4; r4++) {
                        float v = t[r4];
                        if (domask && (r * 128 + kmc + s * 4 + r4 * 16 > qg))
                            v = NEG_INF;
                        e[r4] = __builtin_amdgcn_exp2f(v);
                    }
                    sacc[m] += (e[0] + e[1]) + (e[2] + e[3]);
                    union { unsigned int u[2]; short4_t s4; } pb;
                    pb.u[0] = cvtpk(e[0], e[1]);
                    pb.u[1] = cvtpk(e[2], e[3]);
                    pT[m][s] = pb.s4;
                }
            }

            // PV: O^T[d][q] += V^T-frag * P^T-frag (16x16x16, both in pos space)
            #pragma unroll
            for (int t4 = 0; t4 < 4; t4++)
                #pragma unroll
                for (int s = 0; s < 2; s++) {
                    short4_t vf = *(const short4_t*)&Vb[voff[t4][s]];
                    o[0][t4] = mfma16x16(vf, pT[0][s], o[0][t4]);
                    o[1][t4] = mfma16x16(vf, pT[1][s], o[1][t4]);
                }
        }

#if !HAVE_MFMA16K
        asm volatile("s_nop 7\n\ts_nop 7" ::: "memory");  // drain asm MFMA pipe
#endif
        // reduce sacc across quads (keys of this quarter fully summed)
        #pragma unroll
        for (int m = 0; m < 2; m++) {
            sacc[m] += __shfl_xor(sacc[m], 16);
            sacc[m] += __shfl_xor(sacc[m], 32);
        }

        // 4-way merge through Ml (aliases K/V LDS; rounds done, barriers
        // separate all uses).
        __syncthreads();
        if (qtr != 0) {
            float* dst = sm.Ml + (size_t)((qtr - 1) * 256 + sub * 64 + lane) * 35;
            #pragma unroll
            for (int m = 0; m < 2; m++)
                #pragma unroll
                for (int t4 = 0; t4 < 4; t4++)
                    *(f32x4*)(dst + (m * 4 + t4) * 4) = o[m][t4];
            dst[32] = sacc[0];
            dst[33] = sacc[1];
        }
        __syncthreads();
        if (qtr == 0) {
            #pragma unroll
            for (int j = 0; j < 3; j++) {
                const float* src = sm.Ml + (size_t)(j * 256 + sub * 64 + lane) * 35;
                #pragma unroll
                for (int m = 0; m < 2; m++)
                    #pragma unroll
                    for (int t4 = 0; t4 < 4; t4++)
                        o[m][t4] += *(const f32x4*)(src + (m * 4 + t4) * 4);
                sacc[0] += src[32];
                sacc[1] += src[33];
            }
            #pragma unroll
            for (int m = 0; m < 2; m++) {
                const float inv = 1.0f / sacc[m];
                ushort_t* orow = O + (size_t)(qrow0 + m * 16 + l16) * Dm + h * HD;
                #pragma unroll
                for (int t4 = 0; t4 < 4; t4++) {
                    ushort_t pk[4];
                    #pragma unroll
                    for (int r4 = 0; r4 < 4; r4++)
                        pk[r4] = f2bf(o[m][t4][r4] * inv);
                    *(uint2*)(orow + t4 * 16 + quad * 4) = *(const uint2*)pk;
                }
            }
        }
        __syncthreads();
    }
}

// ---------------- proj GEMM: 128x64 tiles (512 blocks = 2/CU) ----------------
__global__ void __launch_bounds__(256)
gemm_proj(const ushort_t* __restrict__ A, const ushort_t* __restrict__ Bt,
          const float* __restrict__ bias, float* __restrict__ C) {
    __shared__ alignas(16) ushort_t Alds[128 * 32];
    __shared__ alignas(16) ushort_t Blds[64 * 32];
    const int tid  = threadIdx.x;
    const int lane = tid & 63;
    const int w    = tid >> 6;
    const int quad = lane >> 4;
    const int l16  = lane & 15;
    const int mbase = blockIdx.x * 128;
    const int nbase = blockIdx.y * 64;
    const int moff  = (w >> 1) * 64;
    const int noff  = (w & 1) * 32;
    const int K = Dm, N = Dm;

    f32x4 acc[4][2] = {};

    for (int kb = 0; kb < K; kb += 32) {
        __syncthreads();
        #pragma unroll
        for (int c = 0; c < 2; c++) {
            int id  = w * 128 + c * 64 + lane;
            int row = id >> 2, col = (id & 3) * 8;
            gl2lds16(&A[(size_t)(mbase + row) * K + kb + col], &Alds[(size_t)(w * 128 + c * 64) * 8]);
        }
        {
            int id  = w * 64 + lane;
            int row = id >> 2, col = (id & 3) * 8;
            gl2lds16(&Bt[(size_t)(nbase + row) * K + kb + col], &Blds[(size_t)(w * 64) * 8]);
        }
        __syncthreads();
        short8 a[4], b[2];
        #pragma unroll
        for (int m = 0; m < 4; m++)
            a[m] = *(const short8*)&Alds[(moff + m * 16 + l16) * 32 + quad * 8];
        #pragma unroll
        for (int n = 0; n < 2; n++)
            b[n] = *(const short8*)&Blds[(noff + n * 16 + l16) * 32 + quad * 8];
        #pragma unroll
        for (int m = 0; m < 4; m++)
            #pragma unroll
            for (int n = 0; n < 2; n++)
                acc[m][n] = MFMA16(a[m], b[n], acc[m][n]);
    }

    #pragma unroll
    for (int m = 0; m < 4; m++)
        #pragma unroll
        for (int n = 0; n < 2; n++)
            #pragma unroll
            for (int r = 0; r < 4; r++) {
                int row = mbase + moff + m * 16 + quad * 4 + r;
                int col = nbase + noff + n * 16 + l16;
                C[(size_t)row * N + col] = acc[m][n][r] + bias[col];
            }
}

// ---------------- launch ----------------
extern "C" void kernel_launch(void* const* d_in, const int* in_sizes, int n_in,
                              void* d_out, int out_size, void* d_ws, size_t ws_size,
                              hipStream_t stream) {
    const float* X     = (const float*)d_in[0];
    const float* Wqkv  = (const float*)d_in[1];
    const float* bqkv  = (const float*)d_in[2];
    const float* Wproj = (const float*)d_in[3];
    const float* bproj = (const float*)d_in[4];
    float* out = (float*)d_out;

    ushort_t* ws     = (ushort_t*)d_ws;
    ushort_t* Xb     = ws;                               // 4096x1024
    ushort_t* WqkvT  = Xb + (size_t)Lq * Dm;             // 3072x1024
    ushort_t* WprojT = WqkvT + (size_t)D3 * Dm;          // 1024x1024
    ushort_t* qkvB   = WprojT + (size_t)Dm * Dm;         // 4096x3072 (Q,K used)
    ushort_t* VtB    = qkvB + (size_t)Lq * D3;           // 16x64x4096
    ushort_t* Ob     = VtB + (size_t)NH * HD * Lq;       // 4096x1024

    prep<<<dim3(8192), 256, 0, stream>>>(X, Wqkv, Wproj, Xb, WqkvT, WprojT);

    gemm_qkv<<<dim3(Lq / 128, D3 / 128), 256, 0, stream>>>(
        Xb, WqkvT, bqkv, qkvB, VtB);

    attn_fwd<<<dim3(256), 1024, 0, stream>>>(qkvB, VtB, Ob);

    gemm_proj<<<dim3(Lq / 128, Dm / 64), 256, 0, stream>>>(
        Ob, WprojT, bproj, out);
}

// Round 3
// 205.571 us; speedup vs baseline: 1.0468x; 1.0296x over previous
//
#include <hip/hip_runtime.h>
#include <hip/hip_bf16.h>
#include <string.h>

// MultiHeadAttention: B=1, L=4096, D=1024, H=16, HD=64, causal.
// R15 (attn_fwd only, vs R14):
//  - V LDS swizzle now XORs row bit3 into slot bit2 (stage ccV + read voff):
//    lanes l16/l16+8 shared a bank pair in the same 16-lane issue group ->
//    was ~3.2M conflict cycles (tripled vs R12). Now spread.
//  - cvtpk via inline-asm v_cvt_pk_bf16_f32 (1 instr, same RNE bits) instead
//    of header __float22bfloat162_rn (suspected software RNE chain on the
//    exp2->PV critical path).
//  - V fragments hoisted to round top (pure-register PV cluster); QK MFMAs
//    batched before softmax so ds_read latency overlaps compute.
//  - s_setprio(1) around QK and PV MFMA clusters (T5).

typedef unsigned short ushort_t;
typedef __attribute__((ext_vector_type(8))) short short8;
typedef __attribute__((ext_vector_type(4))) short short4_t;
typedef __attribute__((ext_vector_type(4))) float f32x4;

#define MFMA16(a, b, c) __builtin_amdgcn_mfma_f32_16x16x32_bf16(a, b, c, 0, 0, 0)

#if __has_builtin(__builtin_amdgcn_mfma_f32_16x16x16bf16_1k)
#define HAVE_MFMA16K 1
__device__ __forceinline__ f32x4 mfma16x16(short4_t a, short4_t b, f32x4 c) {
    return __builtin_amdgcn_mfma_f32_16x16x16bf16_1k(a, b, c, 0, 0, 0);
}
#else
#define HAVE_MFMA16K 0
__device__ __forceinline__ f32x4 mfma16x16(short4_t a, short4_t b, f32x4 c) {
    asm("s_nop 1\n\tv_mfma_f32_16x16x16_bf16 %0, %1, %2, %0"
        : "+v"(c) : "v"(a), "v"(b));
    return c;
}
#endif

static constexpr int Lq = 4096;
static constexpr int Dm = 1024;
static constexpr int NH = 16;
static constexpr int HD = 64;
static constexpr int D3 = 3072;
static constexpr float SCALE_LOG2E = 0.125f * 1.44269504088896340736f;

__device__ __forceinline__ ushort_t f2bf(float f) {
    union { float f; unsigned int u; } x{f};
    unsigned int u = x.u;
    u += 0x7fffu + ((u >> 16) & 1u);   // RNE
    return (ushort_t)(u >> 16);
}

// packed fp32x2 -> bf16x2, hardware RNE (lo = a, hi = b)
__device__ __forceinline__ unsigned int cvtpk(float a, float b) {
    unsigned int r;
    asm("v_cvt_pk_bf16_f32 %0, %1, %2" : "=v"(r) : "v"(a), "v"(b));
    return r;
}

__device__ __forceinline__ void gl2lds16(const ushort_t* g, ushort_t* l) {
    __builtin_amdgcn_global_load_lds(
        (const __attribute__((address_space(1))) unsigned int*)g,
        (__attribute__((address_space(3))) unsigned int*)l, 16, 0, 0);
}

// ---------------- prep: cvt X->bf16 + transpose-convert both W ----------------
__global__ void __launch_bounds__(256)
prep(const float* __restrict__ X, const float* __restrict__ Wqkv,
     const float* __restrict__ Wproj, ushort_t* __restrict__ Xb,
     ushort_t* __restrict__ WqkvT, ushort_t* __restrict__ WprojT) {
    __shared__ float tile[32][33];
    const int bid = blockIdx.x, tid = threadIdx.x;
    if (bid < 4096) {
        int i = (bid * 256 + tid) * 4;
        float4 v = *(const float4*)&X[i];
        ushort_t r[4] = { f2bf(v.x), f2bf(v.y), f2bf(v.z), f2bf(v.w) };
        *(uint2*)&Xb[i] = *(uint2*)r;
        return;
    }
    const float* W; ushort_t* Wt; int Nd, nb, kb;
    if (bid < 7168) {
        int b = bid - 4096; W = Wqkv;  Wt = WqkvT;  Nd = 3072;
        nb = (b % 96) * 32; kb = (b / 96) * 32;
    } else {
        int b = bid - 7168; W = Wproj; Wt = WprojT; Nd = 1024;
        nb = (b % 32) * 32; kb = (b / 32) * 32;
    }
    const int tx = tid & 31, ty = tid >> 5;
    for (int j = 0; j < 32; j += 8)
        tile[ty + j][tx] = W[(size_t)(kb + ty + j) * Nd + nb + tx];
    __syncthreads();
    for (int j = 0; j < 32; j += 8)
        Wt[(size_t)(nb + ty + j) * Dm + kb + tx] = f2bf(tile[tx][ty + j]);
}

// ---------------- QKV GEMM with fused V-transpose epilogue ----------------
// cols [0,1024): *SCALE_LOG2E -> qkvB (Q); [1024,2048): -> qkvB (K);
// [2048,3072): transposed+key-permuted (pos = rotl2(token) per 64-window) to
// Vt via packed b128 stores.
__global__ void __launch_bounds__(256)
gemm_qkv(const ushort_t* __restrict__ A, const ushort_t* __restrict__ Bt,
         const float* __restrict__ bias, ushort_t* __restrict__ Cq,
         ushort_t* __restrict__ Vt) {
    __shared__ alignas(16) ushort_t Alds[128 * 32];
    __shared__ alignas(16) ushort_t Blds[128 * 32];
    const int tid  = threadIdx.x;
    const int lane = tid & 63;
    const int w    = tid >> 6;
    const int quad = lane >> 4;
    const int l16  = lane & 15;
    const int mbase = blockIdx.x * 128;
    const int nbase = blockIdx.y * 128;
    const int moff  = (w >> 1) * 64;
    const int noff  = (w & 1) * 64;
    const int K = Dm;

    f32x4 acc[4][4] = {};

    for (int kb = 0; kb < K; kb += 32) {
        __syncthreads();
        #pragma unroll
        for (int c = 0; c < 2; c++) {
            int id  = w * 128 + c * 64 + lane;
            int row = id >> 2, col = (id & 3) * 8;
            gl2lds16(&A[(size_t)(mbase + row) * K + kb + col], &Alds[(size_t)(w * 128 + c * 64) * 8]);
            gl2lds16(&Bt[(size_t)(nbase + row) * K + kb + col], &Blds[(size_t)(w * 128 + c * 64) * 8]);
        }
        __syncthreads();
        short8 a[4], b[4];
        #pragma unroll
        for (int m = 0; m < 4; m++)
            a[m] = *(const short8*)&Alds[(moff + m * 16 + l16) * 32 + quad * 8];
        #pragma unroll
        for (int n = 0; n < 4; n++)
            b[n] = *(const short8*)&Blds[(noff + n * 16 + l16) * 32 + quad * 8];
        #pragma unroll
        for (int m = 0; m < 4; m++)
            #pragma unroll
            for (int n = 0; n < 4; n++)
                acc[m][n] = MFMA16(a[m], b[n], acc[m][n]);
    }

    if (nbase < 2048) {
        const bool qscale = (nbase < 1024);
        #pragma unroll
        for (int m = 0; m < 4; m++)
            #pragma unroll
            for (int n = 0; n < 4; n++)
                #pragma unroll
                for (int r = 0; r < 4; r++) {
                    int row = mbase + moff + m * 16 + quad * 4 + r;
                    int col = nbase + noff + n * 16 + l16;
                    float v = acc[m][n][r] + bias[col];
                    if (qscale) v *= SCALE_LOG2E;
                    Cq[(size_t)row * D3 + col] = f2bf(v);
                }
    } else {
        // V block: token64 = m*16 + quad*4 + r -> pos = (quad*4+r)*4 + m.
        // For fixed (quad, r-pair): m-registers give 8 consecutive positions.
        const int dbase = nbase - 2048 + noff;
        const size_t kb0 = (size_t)mbase + moff;   // 64-aligned key window
        #pragma unroll
        for (int n = 0; n < 4; n++) {
            const float bv = bias[nbase + noff + n * 16 + l16];
            ushort_t* vrow = Vt + (size_t)(dbase + n * 16 + l16) * Lq + kb0 + quad * 16;
            #pragma unroll
            for (int rp = 0; rp < 2; rp++) {
                ushort_t pk[8];
                #pragma unroll
                for (int dr = 0; dr < 2; dr++)
                    #pragma unroll
                    for (int m = 0; m < 4; m++)
                        pk[dr * 4 + m] = f2bf(acc[m][n][2 * rp + dr] + bv);
                *(short8*)(vrow + rp * 8) = *(const short8*)pk;
            }
        }
    }
}

// ---------------- flash attention (R15) ----------------
// grid 256 = 16 pairs x 16 heads; head = bid & 15 (XCD pin); p = bid >> 4.
// block 1024 = 16 waves: sub = w&3 (32 q-rows), qtr = w>>2 (32 key-positions).
// sel 0: chunk p; sel 1: chunk 31-p => 33 rounds/block, uniform.
// Position space: Vt stores pos = rotl2(token) per 64-window; K rows are fed
// through token = rotr2(pos) so S^T is position-indexed; mask by true token.
// PV consumes exp2'd scores in-register via 16x16x16 MFMA (B-frag == S^T
// layout). 4-way merge (o, sacc) through Ml union region.
__global__ void __launch_bounds__(1024)
attn_fwd(const ushort_t* __restrict__ qkv, const ushort_t* __restrict__ Vt,
         ushort_t* __restrict__ O) {
    union SMem {
        struct { ushort_t K[2][2][64 * 64]; ushort_t V[2][2][64 * 64]; } kv;
        float Ml[3 * 256 * 35];             // 34 floats/thread, pitch 35
    };
    __shared__ SMem sm;

    const int tid  = threadIdx.x;
    const int lane = tid & 63;
    const int w    = tid >> 6;          // [0,16)
    const int qtr  = w >> 2;            // key quarter [0,4)
    const int sub  = w & 3;             // q sub-chunk (32 rows)
    const int quad = lane >> 4;
    const int l16  = lane & 15;
    const int bid  = blockIdx.x;
    const int h    = bid & 15;
    const int p    = bid >> 4;          // [0,16)
    const float NEG_INF = -__builtin_inff();

    const ushort_t* kbase = qkv + Dm + h * HD;           // K rows, stride D3
    const ushort_t* vbase = Vt + (size_t)h * HD * Lq;    // V^T rows, stride Lq

    // K fragment offsets: A-row i <-> pos = (qtr&1)*32 + s*16 + i, LDS row =
    // token = rotr2(pos) = (i&3)*16 + (qtr&1)*8 + s*4 + (i>>2), i = l16.
    // K staging swizzle f(tok) = ((tok>>4)&3)*2 + (tok&1) spreads the 16
    // fragment rows over all 8 column groups (conflict-free b128).
    int koff[2][2];
    #pragma unroll
    for (int s = 0; s < 2; s++) {
        const int tok = (l16 & 3) * 16 + (qtr & 1) * 8 + s * 4 + (l16 >> 2);
        const int fk  = ((l16 & 3) << 1) | ((l16 >> 2) & 1);
        #pragma unroll
        for (int kh = 0; kh < 2; kh++)
            koff[s][kh] = tok * 64 + (((kh * 4 + quad) ^ fk) * 8);
    }
    // V fragment offsets: natural stored positions, rows = d. Slot swizzle
    // includes row bit3 (-> bit2 of slot) so lanes l16/l16+8 differ.
    int voff[4][2];
    #pragma unroll
    for (int t4 = 0; t4 < 4; t4++)
        #pragma unroll
        for (int s = 0; s < 2; s++) {
            const int row = t4 * 16 + l16;
            const int g = (qtr & 1) * 4 + s * 2 + (quad >> 1);
            const int sx = (row & 7) ^ (((row >> 3) & 1) << 2);
            voff[t4][s] = row * 64 + ((g ^ sx) * 8) + (quad & 1) * 4;
        }
    // true token of st[.][s][r4] within round: r*128 + kmc + s*4 + r4*16
    const int kmc = (qtr >> 1) * 64 + (qtr & 1) * 8 + quad;

    // staging: waves 0-7 stage K (both 64-tiles), waves 8-15 stage V.
    const int  tv  = tid & 511;
    const int  rr  = tv >> 3;
    const int  ccK = (tv & 7) ^ ((((rr >> 4) & 3) << 1) | (rr & 1));
    const int  ccV = (tv & 7) ^ ((rr & 7) ^ (((rr >> 3) & 1) << 2));
    const bool isK = (tid < 512);
    const int  dsto = (w & 7) * 512;
    const ushort_t* kse = kbase + (size_t)rr * D3 + ccK * 8;
    const ushort_t* vse = vbase + (size_t)rr * Lq + ccV * 8;

    for (int sel = 0; sel < 2; sel++) {
        const int c      = sel ? (31 - p) : p;
        const int qc     = c * 128;
        const int rounds = c + 1;
        const int qrow0  = qc + sub * 32;

        short8 qf[2][2];
        #pragma unroll
        for (int m = 0; m < 2; m++) {
            const ushort_t* qr = qkv + (size_t)(qrow0 + m * 16 + l16) * D3 + h * HD;
            qf[m][0] = *(const short8*)(qr + quad * 8);
            qf[m][1] = *(const short8*)(qr + 32 + quad * 8);
        }

        f32x4 o[2][4] = {};
        float sacc[2] = { 0.f, 0.f };

        const ushort_t* kp = kse;
        const ushort_t* vp = vse;

        auto stage = [&](int b) {
            if (isK) {
                gl2lds16(kp,           &sm.kv.K[0][b][dsto]);
                gl2lds16(kp + 64 * D3, &sm.kv.K[1][b][dsto]);
            } else {
                gl2lds16(vp,           &sm.kv.V[0][b][dsto]);
                gl2lds16(vp + 64,      &sm.kv.V[1][b][dsto]);
            }
            kp += (size_t)128 * D3;
            vp += 128;
        };

        stage(0);

        for (int r = 0; r < rounds; r++) {
            const int buf = r & 1;
            __syncthreads();
            if (r + 1 < rounds) stage(buf ^ 1);

            const ushort_t* Kb = &sm.kv.K[qtr >> 1][buf][0];
            const ushort_t* Vb = &sm.kv.V[qtr >> 1][buf][0];
            const bool domask = (r == rounds - 1);

            // hoist all fragment loads: PV becomes a pure-register cluster
            short8 kf[2][2];
            #pragma unroll
            for (int s = 0; s < 2; s++)
                #pragma unroll
                for (int kh = 0; kh < 2; kh++)
                    kf[s][kh] = *(const short8*)&Kb[koff[s][kh]];
            short4_t vf[4][2];
            #pragma unroll
            for (int t4 = 0; t4 < 4; t4++)
                #pragma unroll
                for (int s = 0; s < 2; s++)
                    vf[t4][s] = *(const short4_t*)&Vb[voff[t4][s]];

            // S^T = K * Q^T (position-indexed rows), all 8 MFMAs batched
            f32x4 st[2][2];
            __builtin_amdgcn_s_setprio(1);
            #pragma unroll
            for (int m = 0; m < 2; m++)
                #pragma unroll
                for (int s = 0; s < 2; s++) {
                    f32x4 t = {};
                    t = MFMA16(kf[s][0], qf[m][0], t);
                    t = MFMA16(kf[s][1], qf[m][1], t);
                    st[m][s] = t;
                }
            __builtin_amdgcn_s_setprio(0);

            // exp2 + pack in-register (hw v_cvt_pk_bf16_f32)
            short4_t pT[2][2];
            #pragma unroll
            for (int m = 0; m < 2; m++) {
                const int qg = qrow0 + m * 16 + l16;
                #pragma unroll
                for (int s = 0; s < 2; s++) {
                    float e[4];
                    #pragma unroll
                    for (int r4 = 0; r4 < 4; r4++) {
                        float v = st[m][s][r4];
                        if (domask && (r * 128 + kmc + s * 4 + r4 * 16 > qg))
                            v = NEG_INF;
                        e[r4] = __builtin_amdgcn_exp2f(v);
                    }
                    sacc[m] += (e[0] + e[1]) + (e[2] + e[3]);
                    union { unsigned int u[2]; short4_t s4; } pb;
                    pb.u[0] = cvtpk(e[0], e[1]);
                    pb.u[1] = cvtpk(e[2], e[3]);
                    pT[m][s] = pb.s4;
                }
            }

            // PV: O^T[d][q] += V^T-frag * P^T-frag (16x16x16, pos space)
            __builtin_amdgcn_s_setprio(1);
            #pragma unroll
            for (int t4 = 0; t4 < 4; t4++)
                #pragma unroll
                for (int s = 0; s < 2; s++) {
                    o[0][t4] = mfma16x16(vf[t4][s], pT[0][s], o[0][t4]);
                    o[1][t4] = mfma16x16(vf[t4][s], pT[1][s], o[1][t4]);
                }
            __builtin_amdgcn_s_setprio(0);
        }

#if !HAVE_MFMA16K
        asm volatile("s_nop 7\n\ts_nop 7" ::: "memory");  // drain asm MFMA pipe
#endif
        // reduce sacc across quads (keys of this quarter fully summed)
        #pragma unroll
        for (int m = 0; m < 2; m++) {
            sacc[m] += __shfl_xor(sacc[m], 16);
            sacc[m] += __shfl_xor(sacc[m], 32);
        }

        // 4-way merge through Ml (aliases K/V LDS; rounds done, barriers
        // separate all uses).
        __syncthreads();
        if (qtr != 0) {
            float* dst = sm.Ml + (size_t)((qtr - 1) * 256 + sub * 64 + lane) * 35;
            #pragma unroll
            for (int m = 0; m < 2; m++)
                #pragma unroll
                for (int t4 = 0; t4 < 4; t4++)
                    *(f32x4*)(dst + (m * 4 + t4) * 4) = o[m][t4];
            dst[32] = sacc[0];
            dst[33] = sacc[1];
        }
        __syncthreads();
        if (qtr == 0) {
            #pragma unroll
            for (int j = 0; j < 3; j++) {
                const float* src = sm.Ml + (size_t)(j * 256 + sub * 64 + lane) * 35;
                #pragma unroll
                for (int m = 0; m < 2; m++)
                    #pragma unroll
                    for (int t4 = 0; t4 < 4; t4++)
                        o[m][t4] += *(const f32x4*)(src + (m * 4 + t4) * 4);
                sacc[0] += src[32];
                sacc[1] += src[33];
            }
            #pragma unroll
            for (int m = 0; m < 2; m++) {
                const float inv = 1.0f / sacc[m];
                ushort_t* orow = O + (size_t)(qrow0 + m * 16 + l16) * Dm + h * HD;
                #pragma unroll
                for (int t4 = 0; t4 < 4; t4++) {
                    ushort_t pk[4];
                    #pragma unroll
                    for (int r4 = 0; r4 < 4; r4++)
                        pk[r4] = f2bf(o[m][t4][r4] * inv);
                    *(uint2*)(orow + t4 * 16 + quad * 4) = *(const uint2*)pk;
                }
            }
        }
        __syncthreads();
    }
}

// ---------------- proj GEMM: 128x64 tiles (512 blocks = 2/CU) ----------------
__global__ void __launch_bounds__(256)
gemm_proj(const ushort_t* __restrict__ A, const ushort_t* __restrict__ Bt,
          const float* __restrict__ bias, float* __restrict__ C) {
    __shared__ alignas(16) ushort_t Alds[128 * 32];
    __shared__ alignas(16) ushort_t Blds[64 * 32];
    const int tid  = threadIdx.x;
    const int lane = tid & 63;
    const int w    = tid >> 6;
    const int quad = lane >> 4;
    const int l16  = lane & 15;
    const int mbase = blockIdx.x * 128;
    const int nbase = blockIdx.y * 64;
    const int moff  = (w >> 1) * 64;
    const int noff  = (w & 1) * 32;
    const int K = Dm, N = Dm;

    f32x4 acc[4][2] = {};

    for (int kb = 0; kb < K; kb += 32) {
        __syncthreads();
        #pragma unroll
        for (int c = 0; c < 2; c++) {
            int id  = w * 128 + c * 64 + lane;
            int row = id >> 2, col = (id & 3) * 8;
            gl2lds16(&A[(size_t)(mbase + row) * K + kb + col], &Alds[(size_t)(w * 128 + c * 64) * 8]);
        }
        {
            int id  = w * 64 + lane;
            int row = id >> 2, col = (id & 3) * 8;
            gl2lds16(&Bt[(size_t)(nbase + row) * K + kb + col], &Blds[(size_t)(w * 64) * 8]);
        }
        __syncthreads();
        short8 a[4], b[2];
        #pragma unroll
        for (int m = 0; m < 4; m++)
            a[m] = *(const short8*)&Alds[(moff + m * 16 + l16) * 32 + quad * 8];
        #pragma unroll
        for (int n = 0; n < 2; n++)
            b[n] = *(const short8*)&Blds[(noff + n * 16 + l16) * 32 + quad * 8];
        #pragma unroll
        for (int m = 0; m < 4; m++)
            #pragma unroll
            for (int n = 0; n < 2; n++)
                acc[m][n] = MFMA16(a[m], b[n], acc[m][n]);
    }

    #pragma unroll
    for (int m = 0; m < 4; m++)
        #pragma unroll
        for (int n = 0; n < 2; n++)
            #pragma unroll
            for (int r = 0; r < 4; r++) {
                int row = mbase + moff + m * 16 + quad * 4 + r;
                int col = nbase + noff + n * 16 + l16;
                C[(size_t)row * N + col] = acc[m][n][r] + bias[col];
            }
}

// ---------------- launch ----------------
extern "C" void kernel_launch(void* const* d_in, const int* in_sizes, int n_in,
                              void* d_out, int out_size, void* d_ws, size_t ws_size,
                              hipStream_t stream) {
    const float* X     = (const float*)d_in[0];
    const float* Wqkv  = (const float*)d_in[1];
    const float* bqkv  = (const float*)d_in[2];
    const float* Wproj = (const float*)d_in[3];
    const float* bproj = (const float*)d_in[4];
    float* out = (float*)d_out;

    ushort_t* ws     = (ushort_t*)d_ws;
    ushort_t* Xb     = ws;                               // 4096x1024
    ushort_t* WqkvT  = Xb + (size_t)Lq * Dm;             // 3072x1024
    ushort_t* WprojT = WqkvT + (size_t)D3 * Dm;          // 1024x1024
    ushort_t* qkvB   = WprojT + (size_t)Dm * Dm;         // 4096x3072 (Q,K used)
    ushort_t* VtB    = qkvB + (size_t)Lq * D3;           // 16x64x4096
    ushort_t* Ob     = VtB + (size_t)NH * HD * Lq;       // 4096x1024

    prep<<<dim3(8192), 256, 0, stream>>>(X, Wqkv, Wproj, Xb, WqkvT, WprojT);

    gemm_qkv<<<dim3(Lq / 128, D3 / 128), 256, 0, stream>>>(
        Xb, WqkvT, bqkv, qkvB, VtB);

    attn_fwd<<<dim3(256), 1024, 0, stream>>>(qkvB, VtB, Ob);

    gemm_proj<<<dim3(Lq / 128, Dm / 64), 256, 0, stream>>>(
        Ob, WprojT, bproj, out);
}

// Round 4
// 196.561 us; speedup vs baseline: 1.0948x; 1.0458x over previous
//
#include <hip/hip_runtime.h>
#include <hip/hip_bf16.h>
#include <string.h>

// MultiHeadAttention: B=1, L=4096, D=1024, H=16, HD=64, causal.
// R16 (GEMM-side probe; attn_fwd/prep identical to R15):
//  - gemm_qkv/gemm_proj: BK=64 via two-plane LDS [2][rows][32] (keeps 64B-row
//    layout -> same bank behavior as before, no new swizzle). Halves barrier
//    density: 32 (qkv) / 16 (proj) MFMA per barrier pair.
//  - Bijective chunked XCD swizzle on both GEMM grids (768/512 blocks, %8==0):
//    consecutive blocks per XCD share the B-panel -> B stays L2-resident.
//  - __launch_bounds__ min-waves set to actual residency (3 resp. 2 blk/CU).

typedef unsigned short ushort_t;
typedef __attribute__((ext_vector_type(8))) short short8;
typedef __attribute__((ext_vector_type(4))) short short4_t;
typedef __attribute__((ext_vector_type(4))) float f32x4;

#define MFMA16(a, b, c) __builtin_amdgcn_mfma_f32_16x16x32_bf16(a, b, c, 0, 0, 0)

#if __has_builtin(__builtin_amdgcn_mfma_f32_16x16x16bf16_1k)
#define HAVE_MFMA16K 1
__device__ __forceinline__ f32x4 mfma16x16(short4_t a, short4_t b, f32x4 c) {
    return __builtin_amdgcn_mfma_f32_16x16x16bf16_1k(a, b, c, 0, 0, 0);
}
#else
#define HAVE_MFMA16K 0
__device__ __forceinline__ f32x4 mfma16x16(short4_t a, short4_t b, f32x4 c) {
    asm("s_nop 1\n\tv_mfma_f32_16x16x16_bf16 %0, %1, %2, %0"
        : "+v"(c) : "v"(a), "v"(b));
    return c;
}
#endif

static constexpr int Lq = 4096;
static constexpr int Dm = 1024;
static constexpr int NH = 16;
static constexpr int HD = 64;
static constexpr int D3 = 3072;
static constexpr float SCALE_LOG2E = 0.125f * 1.44269504088896340736f;

__device__ __forceinline__ ushort_t f2bf(float f) {
    union { float f; unsigned int u; } x{f};
    unsigned int u = x.u;
    u += 0x7fffu + ((u >> 16) & 1u);   // RNE
    return (ushort_t)(u >> 16);
}

// packed fp32x2 -> bf16x2, hardware RNE (lo = a, hi = b)
__device__ __forceinline__ unsigned int cvtpk(float a, float b) {
    unsigned int r;
    asm("v_cvt_pk_bf16_f32 %0, %1, %2" : "=v"(r) : "v"(a), "v"(b));
    return r;
}

__device__ __forceinline__ void gl2lds16(const ushort_t* g, ushort_t* l) {
    __builtin_amdgcn_global_load_lds(
        (const __attribute__((address_space(1))) unsigned int*)g,
        (__attribute__((address_space(3))) unsigned int*)l, 16, 0, 0);
}

// ---------------- prep: cvt X->bf16 + transpose-convert both W ----------------
__global__ void __launch_bounds__(256)
prep(const float* __restrict__ X, const float* __restrict__ Wqkv,
     const float* __restrict__ Wproj, ushort_t* __restrict__ Xb,
     ushort_t* __restrict__ WqkvT, ushort_t* __restrict__ WprojT) {
    __shared__ float tile[32][33];
    const int bid = blockIdx.x, tid = threadIdx.x;
    if (bid < 4096) {
        int i = (bid * 256 + tid) * 4;
        float4 v = *(const float4*)&X[i];
        ushort_t r[4] = { f2bf(v.x), f2bf(v.y), f2bf(v.z), f2bf(v.w) };
        *(uint2*)&Xb[i] = *(uint2*)r;
        return;
    }
    const float* W; ushort_t* Wt; int Nd, nb, kb;
    if (bid < 7168) {
        int b = bid - 4096; W = Wqkv;  Wt = WqkvT;  Nd = 3072;
        nb = (b % 96) * 32; kb = (b / 96) * 32;
    } else {
        int b = bid - 7168; W = Wproj; Wt = WprojT; Nd = 1024;
        nb = (b % 32) * 32; kb = (b / 32) * 32;
    }
    const int tx = tid & 31, ty = tid >> 5;
    for (int j = 0; j < 32; j += 8)
        tile[ty + j][tx] = W[(size_t)(kb + ty + j) * Nd + nb + tx];
    __syncthreads();
    for (int j = 0; j < 32; j += 8)
        Wt[(size_t)(nb + ty + j) * Dm + kb + tx] = f2bf(tile[tx][ty + j]);
}

// ---------------- QKV GEMM (BK=64, XCD-swizzled) ----------------
// cols [0,1024): *SCALE_LOG2E -> qkvB (Q); [1024,2048): -> qkvB (K);
// [2048,3072): transposed+key-permuted (pos = rotl2(token) per 64-window) to
// Vt via packed b128 stores.
__global__ void __launch_bounds__(256, 3)
gemm_qkv(const ushort_t* __restrict__ A, const ushort_t* __restrict__ Bt,
         const float* __restrict__ bias, ushort_t* __restrict__ Cq,
         ushort_t* __restrict__ Vt) {
    __shared__ alignas(16) ushort_t Alds[2][128 * 32];   // [kplane][row*32+cc*8]
    __shared__ alignas(16) ushort_t Blds[2][128 * 32];
    const int tid  = threadIdx.x;
    const int lane = tid & 63;
    const int w    = tid >> 6;
    const int quad = lane >> 4;
    const int l16  = lane & 15;
    // chunked XCD swizzle: 768 blocks, 96 consecutive per XCD (bx' fast ->
    // blocks within an XCD share the B-panel).
    const int lin0 = blockIdx.y * 32 + blockIdx.x;
    const int lin  = (lin0 & 7) * 96 + (lin0 >> 3);
    const int mbase = (lin & 31) * 128;
    const int nbase = (lin >> 5) * 128;
    const int moff  = (w >> 1) * 64;
    const int noff  = (w & 1) * 64;
    const int K = Dm;

    f32x4 acc[4][4] = {};

    for (int kb = 0; kb < K; kb += 64) {
        __syncthreads();
        #pragma unroll
        for (int c = 0; c < 4; c++) {
            const int id    = c * 256 + w * 64 + lane;
            const int plane = id >> 9;           // wave-uniform (c>>1)
            const int rem   = id & 511;
            const int row   = rem >> 2, col = (rem & 3) * 8;
            ushort_t* dstA = &Alds[plane][(size_t)((c & 1) * 256 + w * 64) * 8];
            ushort_t* dstB = &Blds[plane][(size_t)((c & 1) * 256 + w * 64) * 8];
            gl2lds16(&A[(size_t)(mbase + row) * K + kb + plane * 32 + col], dstA);
            gl2lds16(&Bt[(size_t)(nbase + row) * K + kb + plane * 32 + col], dstB);
        }
        __syncthreads();
        short8 a[4][2], b[4][2];
        #pragma unroll
        for (int m = 0; m < 4; m++)
            #pragma unroll
            for (int kk = 0; kk < 2; kk++)
                a[m][kk] = *(const short8*)&Alds[kk][(moff + m * 16 + l16) * 32 + quad * 8];
        #pragma unroll
        for (int n = 0; n < 4; n++)
            #pragma unroll
            for (int kk = 0; kk < 2; kk++)
                b[n][kk] = *(const short8*)&Blds[kk][(noff + n * 16 + l16) * 32 + quad * 8];
        #pragma unroll
        for (int kk = 0; kk < 2; kk++)
            #pragma unroll
            for (int m = 0; m < 4; m++)
                #pragma unroll
                for (int n = 0; n < 4; n++)
                    acc[m][n] = MFMA16(a[m][kk], b[n][kk], acc[m][n]);
    }

    if (nbase < 2048) {
        const bool qscale = (nbase < 1024);
        #pragma unroll
        for (int m = 0; m < 4; m++)
            #pragma unroll
            for (int n = 0; n < 4; n++)
                #pragma unroll
                for (int r = 0; r < 4; r++) {
                    int row = mbase + moff + m * 16 + quad * 4 + r;
                    int col = nbase + noff + n * 16 + l16;
                    float v = acc[m][n][r] + bias[col];
                    if (qscale) v *= SCALE_LOG2E;
                    Cq[(size_t)row * D3 + col] = f2bf(v);
                }
    } else {
        // V block: token64 = m*16 + quad*4 + r -> pos = (quad*4+r)*4 + m.
        const int dbase = nbase - 2048 + noff;
        const size_t kb0 = (size_t)mbase + moff;   // 64-aligned key window
        #pragma unroll
        for (int n = 0; n < 4; n++) {
            const float bv = bias[nbase + noff + n * 16 + l16];
            ushort_t* vrow = Vt + (size_t)(dbase + n * 16 + l16) * Lq + kb0 + quad * 16;
            #pragma unroll
            for (int rp = 0; rp < 2; rp++) {
                ushort_t pk[8];
                #pragma unroll
                for (int dr = 0; dr < 2; dr++)
                    #pragma unroll
                    for (int m = 0; m < 4; m++)
                        pk[dr * 4 + m] = f2bf(acc[m][n][2 * rp + dr] + bv);
                *(short8*)(vrow + rp * 8) = *(const short8*)pk;
            }
        }
    }
}

// ---------------- flash attention (R15, unchanged) ----------------
__global__ void __launch_bounds__(1024)
attn_fwd(const ushort_t* __restrict__ qkv, const ushort_t* __restrict__ Vt,
         ushort_t* __restrict__ O) {
    union SMem {
        struct { ushort_t K[2][2][64 * 64]; ushort_t V[2][2][64 * 64]; } kv;
        float Ml[3 * 256 * 35];             // 34 floats/thread, pitch 35
    };
    __shared__ SMem sm;

    const int tid  = threadIdx.x;
    const int lane = tid & 63;
    const int w    = tid >> 6;          // [0,16)
    const int qtr  = w >> 2;            // key quarter [0,4)
    const int sub  = w & 3;             // q sub-chunk (32 rows)
    const int quad = lane >> 4;
    const int l16  = lane & 15;
    const int bid  = blockIdx.x;
    const int h    = bid & 15;
    const int p    = bid >> 4;          // [0,16)
    const float NEG_INF = -__builtin_inff();

    const ushort_t* kbase = qkv + Dm + h * HD;           // K rows, stride D3
    const ushort_t* vbase = Vt + (size_t)h * HD * Lq;    // V^T rows, stride Lq

    int koff[2][2];
    #pragma unroll
    for (int s = 0; s < 2; s++) {
        const int tok = (l16 & 3) * 16 + (qtr & 1) * 8 + s * 4 + (l16 >> 2);
        const int fk  = ((l16 & 3) << 1) | ((l16 >> 2) & 1);
        #pragma unroll
        for (int kh = 0; kh < 2; kh++)
            koff[s][kh] = tok * 64 + (((kh * 4 + quad) ^ fk) * 8);
    }
    int voff[4][2];
    #pragma unroll
    for (int t4 = 0; t4 < 4; t4++)
        #pragma unroll
        for (int s = 0; s < 2; s++) {
            const int row = t4 * 16 + l16;
            const int g = (qtr & 1) * 4 + s * 2 + (quad >> 1);
            const int sx = (row & 7) ^ (((row >> 3) & 1) << 2);
            voff[t4][s] = row * 64 + ((g ^ sx) * 8) + (quad & 1) * 4;
        }
    const int kmc = (qtr >> 1) * 64 + (qtr & 1) * 8 + quad;

    const int  tv  = tid & 511;
    const int  rr  = tv >> 3;
    const int  ccK = (tv & 7) ^ ((((rr >> 4) & 3) << 1) | (rr & 1));
    const int  ccV = (tv & 7) ^ ((rr & 7) ^ (((rr >> 3) & 1) << 2));
    const bool isK = (tid < 512);
    const int  dsto = (w & 7) * 512;
    const ushort_t* kse = kbase + (size_t)rr * D3 + ccK * 8;
    const ushort_t* vse = vbase + (size_t)rr * Lq + ccV * 8;

    for (int sel = 0; sel < 2; sel++) {
        const int c      = sel ? (31 - p) : p;
        const int qc     = c * 128;
        const int rounds = c + 1;
        const int qrow0  = qc + sub * 32;

        short8 qf[2][2];
        #pragma unroll
        for (int m = 0; m < 2; m++) {
            const ushort_t* qr = qkv + (size_t)(qrow0 + m * 16 + l16) * D3 + h * HD;
            qf[m][0] = *(const short8*)(qr + quad * 8);
            qf[m][1] = *(const short8*)(qr + 32 + quad * 8);
        }

        f32x4 o[2][4] = {};
        float sacc[2] = { 0.f, 0.f };

        const ushort_t* kp = kse;
        const ushort_t* vp = vse;

        auto stage = [&](int b) {
            if (isK) {
                gl2lds16(kp,           &sm.kv.K[0][b][dsto]);
                gl2lds16(kp + 64 * D3, &sm.kv.K[1][b][dsto]);
            } else {
                gl2lds16(vp,           &sm.kv.V[0][b][dsto]);
                gl2lds16(vp + 64,      &sm.kv.V[1][b][dsto]);
            }
            kp += (size_t)128 * D3;
            vp += 128;
        };

        stage(0);

        for (int r = 0; r < rounds; r++) {
            const int buf = r & 1;
            __syncthreads();
            if (r + 1 < rounds) stage(buf ^ 1);

            const ushort_t* Kb = &sm.kv.K[qtr >> 1][buf][0];
            const ushort_t* Vb = &sm.kv.V[qtr >> 1][buf][0];
            const bool domask = (r == rounds - 1);

            // hoist all fragment loads: PV becomes a pure-register cluster
            short8 kf[2][2];
            #pragma unroll
            for (int s = 0; s < 2; s++)
                #pragma unroll
                for (int kh = 0; kh < 2; kh++)
                    kf[s][kh] = *(const short8*)&Kb[koff[s][kh]];
            short4_t vf[4][2];
            #pragma unroll
            for (int t4 = 0; t4 < 4; t4++)
                #pragma unroll
                for (int s = 0; s < 2; s++)
                    vf[t4][s] = *(const short4_t*)&Vb[voff[t4][s]];

            // S^T = K * Q^T (position-indexed rows), all 8 MFMAs batched
            f32x4 st[2][2];
            __builtin_amdgcn_s_setprio(1);
            #pragma unroll
            for (int m = 0; m < 2; m++)
                #pragma unroll
                for (int s = 0; s < 2; s++) {
                    f32x4 t = {};
                    t = MFMA16(kf[s][0], qf[m][0], t);
                    t = MFMA16(kf[s][1], qf[m][1], t);
                    st[m][s] = t;
                }
            __builtin_amdgcn_s_setprio(0);

            // exp2 + pack in-register (hw v_cvt_pk_bf16_f32)
            short4_t pT[2][2];
            #pragma unroll
            for (int m = 0; m < 2; m++) {
                const int qg = qrow0 + m * 16 + l16;
                #pragma unroll
                for (int s = 0; s < 2; s++) {
                    float e[4];
                    #pragma unroll
                    for (int r4 = 0; r4 < 4; r4++) {
                        float v = st[m][s][r4];
                        if (domask && (r * 128 + kmc + s * 4 + r4 * 16 > qg))
                            v = NEG_INF;
                        e[r4] = __builtin_amdgcn_exp2f(v);
                    }
                    sacc[m] += (e[0] + e[1]) + (e[2] + e[3]);
                    union { unsigned int u[2]; short4_t s4; } pb;
                    pb.u[0] = cvtpk(e[0], e[1]);
                    pb.u[1] = cvtpk(e[2], e[3]);
                    pT[m][s] = pb.s4;
                }
            }

            // PV: O^T[d][q] += V^T-frag * P^T-frag (16x16x16, pos space)
            __builtin_amdgcn_s_setprio(1);
            #pragma unroll
            for (int t4 = 0; t4 < 4; t4++)
                #pragma unroll
                for (int s = 0; s < 2; s++) {
                    o[0][t4] = mfma16x16(vf[t4][s], pT[0][s], o[0][t4]);
                    o[1][t4] = mfma16x16(vf[t4][s], pT[1][s], o[1][t4]);
                }
            __builtin_amdgcn_s_setprio(0);
        }

#if !HAVE_MFMA16K
        asm volatile("s_nop 7\n\ts_nop 7" ::: "memory");  // drain asm MFMA pipe
#endif
        #pragma unroll
        for (int m = 0; m < 2; m++) {
            sacc[m] += __shfl_xor(sacc[m], 16);
            sacc[m] += __shfl_xor(sacc[m], 32);
        }

        __syncthreads();
        if (qtr != 0) {
            float* dst = sm.Ml + (size_t)((qtr - 1) * 256 + sub * 64 + lane) * 35;
            #pragma unroll
            for (int m = 0; m < 2; m++)
                #pragma unroll
                for (int t4 = 0; t4 < 4; t4++)
                    *(f32x4*)(dst + (m * 4 + t4) * 4) = o[m][t4];
            dst[32] = sacc[0];
            dst[33] = sacc[1];
        }
        __syncthreads();
        if (qtr == 0) {
            #pragma unroll
            for (int j = 0; j < 3; j++) {
                const float* src = sm.Ml + (size_t)(j * 256 + sub * 64 + lane) * 35;
                #pragma unroll
                for (int m = 0; m < 2; m++)
                    #pragma unroll
                    for (int t4 = 0; t4 < 4; t4++)
                        o[m][t4] += *(const f32x4*)(src + (m * 4 + t4) * 4);
                sacc[0] += src[32];
                sacc[1] += src[33];
            }
            #pragma unroll
            for (int m = 0; m < 2; m++) {
                const float inv = 1.0f / sacc[m];
                ushort_t* orow = O + (size_t)(qrow0 + m * 16 + l16) * Dm + h * HD;
                #pragma unroll
                for (int t4 = 0; t4 < 4; t4++) {
                    ushort_t pk[4];
                    #pragma unroll
                    for (int r4 = 0; r4 < 4; r4++)
                        pk[r4] = f2bf(o[m][t4][r4] * inv);
                    *(uint2*)(orow + t4 * 16 + quad * 4) = *(const uint2*)pk;
                }
            }
        }
        __syncthreads();
    }
}

// ---------------- proj GEMM: 128x64 tiles, BK=64, XCD-swizzled ----------------
__global__ void __launch_bounds__(256, 2)
gemm_proj(const ushort_t* __restrict__ A, const ushort_t* __restrict__ Bt,
          const float* __restrict__ bias, float* __restrict__ C) {
    __shared__ alignas(16) ushort_t Alds[2][128 * 32];
    __shared__ alignas(16) ushort_t Blds[2][64 * 32];
    const int tid  = threadIdx.x;
    const int lane = tid & 63;
    const int w    = tid >> 6;
    const int quad = lane >> 4;
    const int l16  = lane & 15;
    // chunked XCD swizzle: 512 blocks, 64 consecutive per XCD.
    const int lin0 = blockIdx.y * 32 + blockIdx.x;
    const int lin  = (lin0 & 7) * 64 + (lin0 >> 3);
    const int mbase = (lin & 31) * 128;
    const int nbase = (lin >> 5) * 64;
    const int moff  = (w >> 1) * 64;
    const int noff  = (w & 1) * 32;
    const int K = Dm, N = Dm;

    f32x4 acc[4][2] = {};

    for (int kb = 0; kb < K; kb += 64) {
        __syncthreads();
        #pragma unroll
        for (int c = 0; c < 4; c++) {
            const int id    = c * 256 + w * 64 + lane;
            const int plane = id >> 9;
            const int rem   = id & 511;
            const int row   = rem >> 2, col = (rem & 3) * 8;
            gl2lds16(&A[(size_t)(mbase + row) * K + kb + plane * 32 + col],
                     &Alds[plane][(size_t)((c & 1) * 256 + w * 64) * 8]);
        }
        #pragma unroll
        for (int c = 0; c < 2; c++) {
            const int id    = c * 256 + w * 64 + lane;
            const int plane = id >> 8;
            const int rem   = id & 255;
            const int row   = rem >> 2, col = (rem & 3) * 8;
            gl2lds16(&Bt[(size_t)(nbase + row) * K + kb + plane * 32 + col],
                     &Blds[plane][(size_t)(w * 64) * 8]);
        }
        __syncthreads();
        short8 a[4][2], b[2][2];
        #pragma unroll
        for (int m = 0; m < 4; m++)
            #pragma unroll
            for (int kk = 0; kk < 2; kk++)
                a[m][kk] = *(const short8*)&Alds[kk][(moff + m * 16 + l16) * 32 + quad * 8];
        #pragma unroll
        for (int n = 0; n < 2; n++)
            #pragma unroll
            for (int kk = 0; kk < 2; kk++)
                b[n][kk] = *(const short8*)&Blds[kk][(noff + n * 16 + l16) * 32 + quad * 8];
        #pragma unroll
        for (int kk = 0; kk < 2; kk++)
            #pragma unroll
            for (int m = 0; m < 4; m++)
                #pragma unroll
                for (int n = 0; n < 2; n++)
                    acc[m][n] = MFMA16(a[m][kk], b[n][kk], acc[m][n]);
    }

    #pragma unroll
    for (int m = 0; m < 4; m++)
        #pragma unroll
        for (int n = 0; n < 2; n++)
            #pragma unroll
            for (int r = 0; r < 4; r++) {
                int row = mbase + moff + m * 16 + quad * 4 + r;
                int col = nbase + noff + n * 16 + l16;
                C[(size_t)row * N + col] = acc[m][n][r] + bias[col];
            }
}

// ---------------- launch ----------------
extern "C" void kernel_launch(void* const* d_in, const int* in_sizes, int n_in,
                              void* d_out, int out_size, void* d_ws, size_t ws_size,
                              hipStream_t stream) {
    const float* X     = (const float*)d_in[0];
    const float* Wqkv  = (const float*)d_in[1];
    const float* bqkv  = (const float*)d_in[2];
    const float* Wproj = (const float*)d_in[3];
    const float* bproj = (const float*)d_in[4];
    float* out = (float*)d_out;

    ushort_t* ws     = (ushort_t*)d_ws;
    ushort_t* Xb     = ws;                               // 4096x1024
    ushort_t* WqkvT  = Xb + (size_t)Lq * Dm;             // 3072x1024
    ushort_t* WprojT = WqkvT + (size_t)D3 * Dm;          // 1024x1024
    ushort_t* qkvB   = WprojT + (size_t)Dm * Dm;         // 4096x3072 (Q,K used)
    ushort_t* VtB    = qkvB + (size_t)Lq * D3;           // 16x64x4096
    ushort_t* Ob     = VtB + (size_t)NH * HD * Lq;       // 4096x1024

    prep<<<dim3(8192), 256, 0, stream>>>(X, Wqkv, Wproj, Xb, WqkvT, WprojT);

    gemm_qkv<<<dim3(Lq / 128, D3 / 128), 256, 0, stream>>>(
        Xb, WqkvT, bqkv, qkvB, VtB);

    attn_fwd<<<dim3(256), 1024, 0, stream>>>(qkvB, VtB, Ob);

    gemm_proj<<<dim3(Lq / 128, Dm / 64), 256, 0, stream>>>(
        Ob, WprojT, bproj, out);
}

// Round 6
// 194.124 us; speedup vs baseline: 1.1086x; 1.0126x over previous
//
#include <hip/hip_runtime.h>
#include <hip/hip_bf16.h>
#include <string.h>

// MultiHeadAttention: B=1, L=4096, D=1024, H=16, HD=64, causal.
// R18: R17 NaN'd despite being semantically identical to R16 -> the failure
// was schedule-sensitive, i.e. the inline-asm 16x16x16 MFMA fallback (compiler
// inserts no MFMA hazard wait-states around opaque asm; R14-R16 passed by
// scheduling luck). This round:
//  - attn: R16's batched round body restored; ONLY the s_setprio brackets are
//    removed (inert A/B of the phase-locking theory).
//  - asm MFMA fallback hardened: s_nop 2 before (VALU-write->MFMA-read) and
//    s_nop 3 after (MFMA-write->VALU-read) each asm MFMA.
//  - gemm_qkv/gemm_proj keep R17's kk-inside operand loads (halved live
//    operand VGPRs under the (256,3)/(256,2) caps; builtin-only, hazard-safe).

typedef unsigned short ushort_t;
typedef __attribute__((ext_vector_type(8))) short short8;
typedef __attribute__((ext_vector_type(4))) short short4_t;
typedef __attribute__((ext_vector_type(4))) float f32x4;

#define MFMA16(a, b, c) __builtin_amdgcn_mfma_f32_16x16x32_bf16(a, b, c, 0, 0, 0)

#if __has_builtin(__builtin_amdgcn_mfma_f32_16x16x16bf16_1k)
#define HAVE_MFMA16K 1
__device__ __forceinline__ f32x4 mfma16x16(short4_t a, short4_t b, f32x4 c) {
    return __builtin_amdgcn_mfma_f32_16x16x16bf16_1k(a, b, c, 0, 0, 0);
}
#else
#define HAVE_MFMA16K 0
__device__ __forceinline__ f32x4 mfma16x16(short4_t a, short4_t b, f32x4 c) {
    asm("s_nop 2\n\tv_mfma_f32_16x16x16_bf16 %0, %1, %2, %0\n\ts_nop 3"
        : "+v"(c) : "v"(a), "v"(b));
    return c;
}
#endif

static constexpr int Lq = 4096;
static constexpr int Dm = 1024;
static constexpr int NH = 16;
static constexpr int HD = 64;
static constexpr int D3 = 3072;
static constexpr float SCALE_LOG2E = 0.125f * 1.44269504088896340736f;

__device__ __forceinline__ ushort_t f2bf(float f) {
    union { float f; unsigned int u; } x{f};
    unsigned int u = x.u;
    u += 0x7fffu + ((u >> 16) & 1u);   // RNE
    return (ushort_t)(u >> 16);
}

// packed fp32x2 -> bf16x2, hardware RNE (lo = a, hi = b)
__device__ __forceinline__ unsigned int cvtpk(float a, float b) {
    unsigned int r;
    asm("v_cvt_pk_bf16_f32 %0, %1, %2" : "=v"(r) : "v"(a), "v"(b));
    return r;
}

__device__ __forceinline__ void gl2lds16(const ushort_t* g, ushort_t* l) {
    __builtin_amdgcn_global_load_lds(
        (const __attribute__((address_space(1))) unsigned int*)g,
        (__attribute__((address_space(3))) unsigned int*)l, 16, 0, 0);
}

// ---------------- prep: cvt X->bf16 + transpose-convert both W ----------------
__global__ void __launch_bounds__(256)
prep(const float* __restrict__ X, const float* __restrict__ Wqkv,
     const float* __restrict__ Wproj, ushort_t* __restrict__ Xb,
     ushort_t* __restrict__ WqkvT, ushort_t* __restrict__ WprojT) {
    __shared__ float tile[32][33];
    const int bid = blockIdx.x, tid = threadIdx.x;
    if (bid < 4096) {
        int i = (bid * 256 + tid) * 4;
        float4 v = *(const float4*)&X[i];
        ushort_t r[4] = { f2bf(v.x), f2bf(v.y), f2bf(v.z), f2bf(v.w) };
        *(uint2*)&Xb[i] = *(uint2*)r;
        return;
    }
    const float* W; ushort_t* Wt; int Nd, nb, kb;
    if (bid < 7168) {
        int b = bid - 4096; W = Wqkv;  Wt = WqkvT;  Nd = 3072;
        nb = (b % 96) * 32; kb = (b / 96) * 32;
    } else {
        int b = bid - 7168; W = Wproj; Wt = WprojT; Nd = 1024;
        nb = (b % 32) * 32; kb = (b / 32) * 32;
    }
    const int tx = tid & 31, ty = tid >> 5;
    for (int j = 0; j < 32; j += 8)
        tile[ty + j][tx] = W[(size_t)(kb + ty + j) * Nd + nb + tx];
    __syncthreads();
    for (int j = 0; j < 32; j += 8)
        Wt[(size_t)(nb + ty + j) * Dm + kb + tx] = f2bf(tile[tx][ty + j]);
}

// ---------------- QKV GEMM (BK=64, XCD-swizzled) ----------------
// cols [0,1024): *SCALE_LOG2E -> qkvB (Q); [1024,2048): -> qkvB (K);
// [2048,3072): transposed+key-permuted (pos = rotl2(token) per 64-window) to
// Vt via packed b128 stores.
__global__ void __launch_bounds__(256, 3)
gemm_qkv(const ushort_t* __restrict__ A, const ushort_t* __restrict__ Bt,
         const float* __restrict__ bias, ushort_t* __restrict__ Cq,
         ushort_t* __restrict__ Vt) {
    __shared__ alignas(16) ushort_t Alds[2][128 * 32];   // [kplane][row*32+cc*8]
    __shared__ alignas(16) ushort_t Blds[2][128 * 32];
    const int tid  = threadIdx.x;
    const int lane = tid & 63;
    const int w    = tid >> 6;
    const int quad = lane >> 4;
    const int l16  = lane & 15;
    // chunked XCD swizzle: 768 blocks, 96 consecutive per XCD.
    const int lin0 = blockIdx.y * 32 + blockIdx.x;
    const int lin  = (lin0 & 7) * 96 + (lin0 >> 3);
    const int mbase = (lin & 31) * 128;
    const int nbase = (lin >> 5) * 128;
    const int moff  = (w >> 1) * 64;
    const int noff  = (w & 1) * 64;
    const int K = Dm;

    f32x4 acc[4][4] = {};

    for (int kb = 0; kb < K; kb += 64) {
        __syncthreads();
        #pragma unroll
        for (int c = 0; c < 4; c++) {
            const int id    = c * 256 + w * 64 + lane;
            const int plane = id >> 9;           // wave-uniform (c>>1)
            const int rem   = id & 511;
            const int row   = rem >> 2, col = (rem & 3) * 8;
            ushort_t* dstA = &Alds[plane][(size_t)((c & 1) * 256 + w * 64) * 8];
            ushort_t* dstB = &Blds[plane][(size_t)((c & 1) * 256 + w * 64) * 8];
            gl2lds16(&A[(size_t)(mbase + row) * K + kb + plane * 32 + col], dstA);
            gl2lds16(&Bt[(size_t)(nbase + row) * K + kb + plane * 32 + col], dstB);
        }
        __syncthreads();
        #pragma unroll
        for (int kk = 0; kk < 2; kk++) {
            short8 a[4], b[4];
            #pragma unroll
            for (int m = 0; m < 4; m++)
                a[m] = *(const short8*)&Alds[kk][(moff + m * 16 + l16) * 32 + quad * 8];
            #pragma unroll
            for (int n = 0; n < 4; n++)
                b[n] = *(const short8*)&Blds[kk][(noff + n * 16 + l16) * 32 + quad * 8];
            #pragma unroll
            for (int m = 0; m < 4; m++)
                #pragma unroll
                for (int n = 0; n < 4; n++)
                    acc[m][n] = MFMA16(a[m], b[n], acc[m][n]);
        }
    }

    if (nbase < 2048) {
        const bool qscale = (nbase < 1024);
        #pragma unroll
        for (int m = 0; m < 4; m++)
            #pragma unroll
            for (int n = 0; n < 4; n++)
                #pragma unroll
                for (int r = 0; r < 4; r++) {
                    int row = mbase + moff + m * 16 + quad * 4 + r;
                    int col = nbase + noff + n * 16 + l16;
                    float v = acc[m][n][r] + bias[col];
                    if (qscale) v *= SCALE_LOG2E;
                    Cq[(size_t)row * D3 + col] = f2bf(v);
                }
    } else {
        // V block: token64 = m*16 + quad*4 + r -> pos = (quad*4+r)*4 + m.
        const int dbase = nbase - 2048 + noff;
        const size_t kb0 = (size_t)mbase + moff;   // 64-aligned key window
        #pragma unroll
        for (int n = 0; n < 4; n++) {
            const float bv = bias[nbase + noff + n * 16 + l16];
            ushort_t* vrow = Vt + (size_t)(dbase + n * 16 + l16) * Lq + kb0 + quad * 16;
            #pragma unroll
            for (int rp = 0; rp < 2; rp++) {
                ushort_t pk[8];
                #pragma unroll
                for (int dr = 0; dr < 2; dr++)
                    #pragma unroll
                    for (int m = 0; m < 4; m++)
                        pk[dr * 4 + m] = f2bf(acc[m][n][2 * rp + dr] + bv);
                *(short8*)(vrow + rp * 8) = *(const short8*)pk;
            }
        }
    }
}

// ---------------- flash attention (R18 = R16 minus setprio) ----------------
// grid 256 = 16 pairs x 16 heads; head = bid & 15 (XCD pin); p = bid >> 4.
// block 1024 = 16 waves: sub = w&3 (32 q-rows), qtr = w>>2 (32 key-positions).
// sel 0: chunk p; sel 1: chunk 31-p => 33 rounds/block, uniform.
// Position space: Vt stores pos = rotl2(token) per 64-window; K rows are fed
// through token = rotr2(pos) so S^T is position-indexed; mask by true token.
__global__ void __launch_bounds__(1024)
attn_fwd(const ushort_t* __restrict__ qkv, const ushort_t* __restrict__ Vt,
         ushort_t* __restrict__ O) {
    union SMem {
        struct { ushort_t K[2][2][64 * 64]; ushort_t V[2][2][64 * 64]; } kv;
        float Ml[3 * 256 * 35];             // 34 floats/thread, pitch 35
    };
    __shared__ SMem sm;

    const int tid  = threadIdx.x;
    const int lane = tid & 63;
    const int w    = tid >> 6;          // [0,16)
    const int qtr  = w >> 2;            // key quarter [0,4)
    const int sub  = w & 3;             // q sub-chunk (32 rows)
    const int quad = lane >> 4;
    const int l16  = lane & 15;
    const int bid  = blockIdx.x;
    const int h    = bid & 15;
    const int p    = bid >> 4;          // [0,16)
    const float NEG_INF = -__builtin_inff();

    const ushort_t* kbase = qkv + Dm + h * HD;           // K rows, stride D3
    const ushort_t* vbase = Vt + (size_t)h * HD * Lq;    // V^T rows, stride Lq

    int koff[2][2];
    #pragma unroll
    for (int s = 0; s < 2; s++) {
        const int tok = (l16 & 3) * 16 + (qtr & 1) * 8 + s * 4 + (l16 >> 2);
        const int fk  = ((l16 & 3) << 1) | ((l16 >> 2) & 1);
        #pragma unroll
        for (int kh = 0; kh < 2; kh++)
            koff[s][kh] = tok * 64 + (((kh * 4 + quad) ^ fk) * 8);
    }
    int voff[4][2];
    #pragma unroll
    for (int t4 = 0; t4 < 4; t4++)
        #pragma unroll
        for (int s = 0; s < 2; s++) {
            const int row = t4 * 16 + l16;
            const int g = (qtr & 1) * 4 + s * 2 + (quad >> 1);
            const int sx = (row & 7) ^ (((row >> 3) & 1) << 2);
            voff[t4][s] = row * 64 + ((g ^ sx) * 8) + (quad & 1) * 4;
        }
    const int kmc = (qtr >> 1) * 64 + (qtr & 1) * 8 + quad;

    const int  tv  = tid & 511;
    const int  rr  = tv >> 3;
    const int  ccK = (tv & 7) ^ ((((rr >> 4) & 3) << 1) | (rr & 1));
    const int  ccV = (tv & 7) ^ ((rr & 7) ^ (((rr >> 3) & 1) << 2));
    const bool isK = (tid < 512);
    const int  dsto = (w & 7) * 512;
    const ushort_t* kse = kbase + (size_t)rr * D3 + ccK * 8;
    const ushort_t* vse = vbase + (size_t)rr * Lq + ccV * 8;

    for (int sel = 0; sel < 2; sel++) {
        const int c      = sel ? (31 - p) : p;
        const int qc     = c * 128;
        const int rounds = c + 1;
        const int qrow0  = qc + sub * 32;

        short8 qf[2][2];
        #pragma unroll
        for (int m = 0; m < 2; m++) {
            const ushort_t* qr = qkv + (size_t)(qrow0 + m * 16 + l16) * D3 + h * HD;
            qf[m][0] = *(const short8*)(qr + quad * 8);
            qf[m][1] = *(const short8*)(qr + 32 + quad * 8);
        }

        f32x4 o[2][4] = {};
        float sacc[2] = { 0.f, 0.f };

        const ushort_t* kp = kse;
        const ushort_t* vp = vse;

        auto stage = [&](int b) {
            if (isK) {
                gl2lds16(kp,           &sm.kv.K[0][b][dsto]);
                gl2lds16(kp + 64 * D3, &sm.kv.K[1][b][dsto]);
            } else {
                gl2lds16(vp,           &sm.kv.V[0][b][dsto]);
                gl2lds16(vp + 64,      &sm.kv.V[1][b][dsto]);
            }
            kp += (size_t)128 * D3;
            vp += 128;
        };

        stage(0);

        for (int r = 0; r < rounds; r++) {
            const int buf = r & 1;
            __syncthreads();
            if (r + 1 < rounds) stage(buf ^ 1);

            const ushort_t* Kb = &sm.kv.K[qtr >> 1][buf][0];
            const ushort_t* Vb = &sm.kv.V[qtr >> 1][buf][0];
            const bool domask = (r == rounds - 1);

            // hoist all fragment loads: PV becomes a pure-register cluster
            short8 kf[2][2];
            #pragma unroll
            for (int s = 0; s < 2; s++)
                #pragma unroll
                for (int kh = 0; kh < 2; kh++)
                    kf[s][kh] = *(const short8*)&Kb[koff[s][kh]];
            short4_t vf[4][2];
            #pragma unroll
            for (int t4 = 0; t4 < 4; t4++)
                #pragma unroll
                for (int s = 0; s < 2; s++)
                    vf[t4][s] = *(const short4_t*)&Vb[voff[t4][s]];

            // S^T = K * Q^T (position-indexed rows), all 8 MFMAs batched
            f32x4 st[2][2];
            #pragma unroll
            for (int m = 0; m < 2; m++)
                #pragma unroll
                for (int s = 0; s < 2; s++) {
                    f32x4 t = {};
                    t = MFMA16(kf[s][0], qf[m][0], t);
                    t = MFMA16(kf[s][1], qf[m][1], t);
                    st[m][s] = t;
                }

            // exp2 + pack in-register (hw v_cvt_pk_bf16_f32)
            short4_t pT[2][2];
            #pragma unroll
            for (int m = 0; m < 2; m++) {
                const int qg = qrow0 + m * 16 + l16;
                #pragma unroll
                for (int s = 0; s < 2; s++) {
                    float e[4];
                    #pragma unroll
                    for (int r4 = 0; r4 < 4; r4++) {
                        float v = st[m][s][r4];
                        if (domask && (r * 128 + kmc + s * 4 + r4 * 16 > qg))
                            v = NEG_INF;
                        e[r4] = __builtin_amdgcn_exp2f(v);
                    }
                    sacc[m] += (e[0] + e[1]) + (e[2] + e[3]);
                    union { unsigned int u[2]; short4_t s4; } pb;
                    pb.u[0] = cvtpk(e[0], e[1]);
                    pb.u[1] = cvtpk(e[2], e[3]);
                    pT[m][s] = pb.s4;
                }
            }

            // PV: O^T[d][q] += V^T-frag * P^T-frag (16x16x16, pos space)
            #pragma unroll
            for (int t4 = 0; t4 < 4; t4++)
                #pragma unroll
                for (int s = 0; s < 2; s++) {
                    o[0][t4] = mfma16x16(vf[t4][s], pT[0][s], o[0][t4]);
                    o[1][t4] = mfma16x16(vf[t4][s], pT[1][s], o[1][t4]);
                }
        }

#if !HAVE_MFMA16K
        asm volatile("s_nop 7\n\ts_nop 7" ::: "memory");  // drain asm MFMA pipe
#endif
        #pragma unroll
        for (int m = 0; m < 2; m++) {
            sacc[m] += __shfl_xor(sacc[m], 16);
            sacc[m] += __shfl_xor(sacc[m], 32);
        }

        __syncthreads();
        if (qtr != 0) {
            float* dst = sm.Ml + (size_t)((qtr - 1) * 256 + sub * 64 + lane) * 35;
            #pragma unroll
            for (int m = 0; m < 2; m++)
                #pragma unroll
                for (int t4 = 0; t4 < 4; t4++)
                    *(f32x4*)(dst + (m * 4 + t4) * 4) = o[m][t4];
            dst[32] = sacc[0];
            dst[33] = sacc[1];
        }
        __syncthreads();
        if (qtr == 0) {
            #pragma unroll
            for (int j = 0; j < 3; j++) {
                const float* src = sm.Ml + (size_t)(j * 256 + sub * 64 + lane) * 35;
                #pragma unroll
                for (int m = 0; m < 2; m++)
                    #pragma unroll
                    for (int t4 = 0; t4 < 4; t4++)
                        o[m][t4] += *(const f32x4*)(src + (m * 4 + t4) * 4);
                sacc[0] += src[32];
                sacc[1] += src[33];
            }
            #pragma unroll
            for (int m = 0; m < 2; m++) {
                const float inv = 1.0f / sacc[m];
                ushort_t* orow = O + (size_t)(qrow0 + m * 16 + l16) * Dm + h * HD;
                #pragma unroll
                for (int t4 = 0; t4 < 4; t4++) {
                    ushort_t pk[4];
                    #pragma unroll
                    for (int r4 = 0; r4 < 4; r4++)
                        pk[r4] = f2bf(o[m][t4][r4] * inv);
                    *(uint2*)(orow + t4 * 16 + quad * 4) = *(const uint2*)pk;
                }
            }
        }
        __syncthreads();
    }
}

// ---------------- proj GEMM: 128x64 tiles, BK=64, XCD-swizzled ----------------
__global__ void __launch_bounds__(256, 2)
gemm_proj(const ushort_t* __restrict__ A, const ushort_t* __restrict__ Bt,
          const float* __restrict__ bias, float* __restrict__ C) {
    __shared__ alignas(16) ushort_t Alds[2][128 * 32];
    __shared__ alignas(16) ushort_t Blds[2][64 * 32];
    const int tid  = threadIdx.x;
    const int lane = tid & 63;
    const int w    = tid >> 6;
    const int quad = lane >> 4;
    const int l16  = lane & 15;
    // chunked XCD swizzle: 512 blocks, 64 consecutive per XCD.
    const int lin0 = blockIdx.y * 32 + blockIdx.x;
    const int lin  = (lin0 & 7) * 64 + (lin0 >> 3);
    const int mbase = (lin & 31) * 128;
    const int nbase = (lin >> 5) * 64;
    const int moff  = (w >> 1) * 64;
    const int noff  = (w & 1) * 32;
    const int K = Dm, N = Dm;

    f32x4 acc[4][2] = {};

    for (int kb = 0; kb < K; kb += 64) {
        __syncthreads();
        #pragma unroll
        for (int c = 0; c < 4; c++) {
            const int id    = c * 256 + w * 64 + lane;
            const int plane = id >> 9;
            const int rem   = id & 511;
            const int row   = rem >> 2, col = (rem & 3) * 8;
            gl2lds16(&A[(size_t)(mbase + row) * K + kb + plane * 32 + col],
                     &Alds[plane][(size_t)((c & 1) * 256 + w * 64) * 8]);
        }
        #pragma unroll
        for (int c = 0; c < 2; c++) {
            const int id    = c * 256 + w * 64 + lane;
            const int plane = id >> 8;
            const int rem   = id & 255;
            const int row   = rem >> 2, col = (rem & 3) * 8;
            gl2lds16(&Bt[(size_t)(nbase + row) * K + kb + plane * 32 + col],
                     &Blds[plane][(size_t)(w * 64) * 8]);
        }
        __syncthreads();
        #pragma unroll
        for (int kk = 0; kk < 2; kk++) {
            short8 a[4], b[2];
            #pragma unroll
            for (int m = 0; m < 4; m++)
                a[m] = *(const short8*)&Alds[kk][(moff + m * 16 + l16) * 32 + quad * 8];
            #pragma unroll
            for (int n = 0; n < 2; n++)
                b[n] = *(const short8*)&Blds[kk][(noff + n * 16 + l16) * 32 + quad * 8];
            #pragma unroll
            for (int m = 0; m < 4; m++)
                #pragma unroll
                for (int n = 0; n < 2; n++)
                    acc[m][n] = MFMA16(a[m], b[n], acc[m][n]);
        }
    }

    #pragma unroll
    for (int m = 0; m < 4; m++)
        #pragma unroll
        for (int n = 0; n < 2; n++)
            #pragma unroll
            for (int r = 0; r < 4; r++) {
                int row = mbase + moff + m * 16 + quad * 4 + r;
                int col = nbase + noff + n * 16 + l16;
                C[(size_t)row * N + col] = acc[m][n][r] + bias[col];
            }
}

// ---------------- launch ----------------
extern "C" void kernel_launch(void* const* d_in, const int* in_sizes, int n_in,
                              void* d_out, int out_size, void* d_ws, size_t ws_size,
                              hipStream_t stream) {
    const float* X     = (const float*)d_in[0];
    const float* Wqkv  = (const float*)d_in[1];
    const float* bqkv  = (const float*)d_in[2];
    const float* Wproj = (const float*)d_in[3];
    const float* bproj = (const float*)d_in[4];
    float* out = (float*)d_out;

    ushort_t* ws     = (ushort_t*)d_ws;
    ushort_t* Xb     = ws;                               // 4096x1024
    ushort_t* WqkvT  = Xb + (size_t)Lq * Dm;             // 3072x1024
    ushort_t* WprojT = WqkvT + (size_t)D3 * Dm;          // 1024x1024
    ushort_t* qkvB   = WprojT + (size_t)Dm * Dm;         // 4096x3072 (Q,K used)
    ushort_t* VtB    = qkvB + (size_t)Lq * D3;           // 16x64x4096
    ushort_t* Ob     = VtB + (size_t)NH * HD * Lq;       // 4096x1024

    prep<<<dim3(8192), 256, 0, stream>>>(X, Wqkv, Wproj, Xb, WqkvT, WprojT);

    gemm_qkv<<<dim3(Lq / 128, D3 / 128), 256, 0, stream>>>(
        Xb, WqkvT, bqkv, qkvB, VtB);

    attn_fwd<<<dim3(256), 1024, 0, stream>>>(qkvB, VtB, Ob);

    gemm_proj<<<dim3(Lq / 128, Dm / 64), 256, 0, stream>>>(
        Ob, WprojT, bproj, out);
}

// Round 7
// 190.899 us; speedup vs baseline: 1.1273x; 1.0169x over previous
//
#include <hip/hip_runtime.h>
#include <hip/hip_bf16.h>
#include <string.h>

// MultiHeadAttention: B=1, L=4096, D=1024, H=16, HD=64, causal.
// R19 (attn only; gemm/prep = R18):
//  - PV upgraded 16x16x16 -> 16x16x32 (8 MFMAs/round instead of 16). Counter
//    arithmetic (R18: MfmaUtil 33% => ~19 cyc/SIMD per PV op) showed the
//    legacy _1k op occupies the matrix pipe per-INSTRUCTION: PV burned 2x its
//    FLOP-necessary pipe cycles on each wave's critical path.
//  - Enabler: re-pick the QK row<->position permutation so chunk s out-row
//    quad*4+r4 == PV-key quad*8+s*4+r4; then pT[m][0]||pT[m][1] is ALREADY a
//    valid K=32 B-frag (k = quad*8 + s*4 + r4) and V reads become 4x b128.
//    Token/position algebra re-derived and checked (rotr2(p) == new tok map).
//  - K staging swizzle g'(rr) = ((rr>>4)&3)<<1 | ((rr>>1)&1) keeps the read
//    slot pattern fk unchanged (8 distinct slots per 8-lane group).
//  - Inline-asm 16x16x16 fallback (R17's NaN source) deleted: all-builtin.

typedef unsigned short ushort_t;
typedef __attribute__((ext_vector_type(8))) short short8;
typedef __attribute__((ext_vector_type(4))) float f32x4;

#define MFMA16(a, b, c) __builtin_amdgcn_mfma_f32_16x16x32_bf16(a, b, c, 0, 0, 0)

static constexpr int Lq = 4096;
static constexpr int Dm = 1024;
static constexpr int NH = 16;
static constexpr int HD = 64;
static constexpr int D3 = 3072;
static constexpr float SCALE_LOG2E = 0.125f * 1.44269504088896340736f;

__device__ __forceinline__ ushort_t f2bf(float f) {
    union { float f; unsigned int u; } x{f};
    unsigned int u = x.u;
    u += 0x7fffu + ((u >> 16) & 1u);   // RNE
    return (ushort_t)(u >> 16);
}

// packed fp32x2 -> bf16x2, hardware RNE (lo = a, hi = b)
__device__ __forceinline__ unsigned int cvtpk(float a, float b) {
    unsigned int r;
    asm("v_cvt_pk_bf16_f32 %0, %1, %2" : "=v"(r) : "v"(a), "v"(b));
    return r;
}

__device__ __forceinline__ void gl2lds16(const ushort_t* g, ushort_t* l) {
    __builtin_amdgcn_global_load_lds(
        (const __attribute__((address_space(1))) unsigned int*)g,
        (__attribute__((address_space(3))) unsigned int*)l, 16, 0, 0);
}

// ---------------- prep: cvt X->bf16 + transpose-convert both W ----------------
__global__ void __launch_bounds__(256)
prep(const float* __restrict__ X, const float* __restrict__ Wqkv,
     const float* __restrict__ Wproj, ushort_t* __restrict__ Xb,
     ushort_t* __restrict__ WqkvT, ushort_t* __restrict__ WprojT) {
    __shared__ float tile[32][33];
    const int bid = blockIdx.x, tid = threadIdx.x;
    if (bid < 4096) {
        int i = (bid * 256 + tid) * 4;
        float4 v = *(const float4*)&X[i];
        ushort_t r[4] = { f2bf(v.x), f2bf(v.y), f2bf(v.z), f2bf(v.w) };
        *(uint2*)&Xb[i] = *(uint2*)r;
        return;
    }
    const float* W; ushort_t* Wt; int Nd, nb, kb;
    if (bid < 7168) {
        int b = bid - 4096; W = Wqkv;  Wt = WqkvT;  Nd = 3072;
        nb = (b % 96) * 32; kb = (b / 96) * 32;
    } else {
        int b = bid - 7168; W = Wproj; Wt = WprojT; Nd = 1024;
        nb = (b % 32) * 32; kb = (b / 32) * 32;
    }
    const int tx = tid & 31, ty = tid >> 5;
    for (int j = 0; j < 32; j += 8)
        tile[ty + j][tx] = W[(size_t)(kb + ty + j) * Nd + nb + tx];
    __syncthreads();
    for (int j = 0; j < 32; j += 8)
        Wt[(size_t)(nb + ty + j) * Dm + kb + tx] = f2bf(tile[tx][ty + j]);
}

// ---------------- QKV GEMM (BK=64, XCD-swizzled) ----------------
// cols [0,1024): *SCALE_LOG2E -> qkvB (Q); [1024,2048): -> qkvB (K);
// [2048,3072): transposed+key-permuted (pos = rotl2(token) per 64-window) to
// Vt via packed b128 stores.
__global__ void __launch_bounds__(256, 3)
gemm_qkv(const ushort_t* __restrict__ A, const ushort_t* __restrict__ Bt,
         const float* __restrict__ bias, ushort_t* __restrict__ Cq,
         ushort_t* __restrict__ Vt) {
    __shared__ alignas(16) ushort_t Alds[2][128 * 32];   // [kplane][row*32+cc*8]
    __shared__ alignas(16) ushort_t Blds[2][128 * 32];
    const int tid  = threadIdx.x;
    const int lane = tid & 63;
    const int w    = tid >> 6;
    const int quad = lane >> 4;
    const int l16  = lane & 15;
    // chunked XCD swizzle: 768 blocks, 96 consecutive per XCD.
    const int lin0 = blockIdx.y * 32 + blockIdx.x;
    const int lin  = (lin0 & 7) * 96 + (lin0 >> 3);
    const int mbase = (lin & 31) * 128;
    const int nbase = (lin >> 5) * 128;
    const int moff  = (w >> 1) * 64;
    const int noff  = (w & 1) * 64;
    const int K = Dm;

    f32x4 acc[4][4] = {};

    for (int kb = 0; kb < K; kb += 64) {
        __syncthreads();
        #pragma unroll
        for (int c = 0; c < 4; c++) {
            const int id    = c * 256 + w * 64 + lane;
            const int plane = id >> 9;           // wave-uniform (c>>1)
            const int rem   = id & 511;
            const int row   = rem >> 2, col = (rem & 3) * 8;
            ushort_t* dstA = &Alds[plane][(size_t)((c & 1) * 256 + w * 64) * 8];
            ushort_t* dstB = &Blds[plane][(size_t)((c & 1) * 256 + w * 64) * 8];
            gl2lds16(&A[(size_t)(mbase + row) * K + kb + plane * 32 + col], dstA);
            gl2lds16(&Bt[(size_t)(nbase + row) * K + kb + plane * 32 + col], dstB);
        }
        __syncthreads();
        #pragma unroll
        for (int kk = 0; kk < 2; kk++) {
            short8 a[4], b[4];
            #pragma unroll
            for (int m = 0; m < 4; m++)
                a[m] = *(const short8*)&Alds[kk][(moff + m * 16 + l16) * 32 + quad * 8];
            #pragma unroll
            for (int n = 0; n < 4; n++)
                b[n] = *(const short8*)&Blds[kk][(noff + n * 16 + l16) * 32 + quad * 8];
            #pragma unroll
            for (int m = 0; m < 4; m++)
                #pragma unroll
                for (int n = 0; n < 4; n++)
                    acc[m][n] = MFMA16(a[m], b[n], acc[m][n]);
        }
    }

    if (nbase < 2048) {
        const bool qscale = (nbase < 1024);
        #pragma unroll
        for (int m = 0; m < 4; m++)
            #pragma unroll
            for (int n = 0; n < 4; n++)
                #pragma unroll
                for (int r = 0; r < 4; r++) {
                    int row = mbase + moff + m * 16 + quad * 4 + r;
                    int col = nbase + noff + n * 16 + l16;
                    float v = acc[m][n][r] + bias[col];
                    if (qscale) v *= SCALE_LOG2E;
                    Cq[(size_t)row * D3 + col] = f2bf(v);
                }
    } else {
        // V block: token64 = m*16 + quad*4 + r -> pos = (quad*4+r)*4 + m.
        const int dbase = nbase - 2048 + noff;
        const size_t kb0 = (size_t)mbase + moff;   // 64-aligned key window
        #pragma unroll
        for (int n = 0; n < 4; n++) {
            const float bv = bias[nbase + noff + n * 16 + l16];
            ushort_t* vrow = Vt + (size_t)(dbase + n * 16 + l16) * Lq + kb0 + quad * 16;
            #pragma unroll
            for (int rp = 0; rp < 2; rp++) {
                ushort_t pk[8];
                #pragma unroll
                for (int dr = 0; dr < 2; dr++)
                    #pragma unroll
                    for (int m = 0; m < 4; m++)
                        pk[dr * 4 + m] = f2bf(acc[m][n][2 * rp + dr] + bv);
                *(short8*)(vrow + rp * 8) = *(const short8*)pk;
            }
        }
    }
}

// ---------------- flash attention (R19: K=32 PV) ----------------
// grid 256 = 16 pairs x 16 heads; head = bid & 15 (XCD pin); p = bid >> 4.
// block 1024 = 16 waves: sub = w&3 (32 q-rows), qtr = w>>2 (32 key-positions).
// sel 0: chunk p; sel 1: chunk 31-p => 33 rounds/block, uniform.
// Key permutation chosen so QK chunk s out-row quad*4+r4 == PV-key
// quad*8+s*4+r4: pT[m][0]||pT[m][1] is directly the K=32 PV B-fragment.
// True token of PV-key: tok = r4*16 + (qtr&1)*8 + quad*2 + s (for masking).
__global__ void __launch_bounds__(1024)
attn_fwd(const ushort_t* __restrict__ qkv, const ushort_t* __restrict__ Vt,
         ushort_t* __restrict__ O) {
    union SMem {
        struct { ushort_t K[2][2][64 * 64]; ushort_t V[2][2][64 * 64]; } kv;
        float Ml[3 * 256 * 35];             // 34 floats/thread, pitch 35
    };
    __shared__ SMem sm;

    const int tid  = threadIdx.x;
    const int lane = tid & 63;
    const int w    = tid >> 6;          // [0,16)
    const int qtr  = w >> 2;            // key quarter [0,4)
    const int sub  = w & 3;             // q sub-chunk (32 rows)
    const int quad = lane >> 4;
    const int l16  = lane & 15;
    const int bid  = blockIdx.x;
    const int h    = bid & 15;
    const int p    = bid >> 4;          // [0,16)
    const float NEG_INF = -__builtin_inff();

    const ushort_t* kbase = qkv + Dm + h * HD;           // K rows, stride D3
    const ushort_t* vbase = Vt + (size_t)h * HD * Lq;    // V^T rows, stride Lq

    // K fragment: A-row i (=l16) of chunk s holds token
    //   tok = (i&3)*16 + (qtr&1)*8 + ((i>>2)&3)*2 + s
    // so that QK out-row quad*4+r4 lands on PV-key quad*8+s*4+r4.
    // Read slot fk matches staging swizzle g'(tok) = ((tok>>4)&3)*2+((tok>>1)&1).
    int koff[2][2];
    #pragma unroll
    for (int s = 0; s < 2; s++) {
        const int tok = (l16 & 3) * 16 + (qtr & 1) * 8 + ((l16 >> 2) & 3) * 2 + s;
        const int fk  = ((l16 & 3) << 1) | ((l16 >> 2) & 1);
        #pragma unroll
        for (int kh = 0; kh < 2; kh++)
            koff[s][kh] = tok * 64 + (((kh * 4 + quad) ^ fk) * 8);
    }
    // V fragment (K=32 A-frag): row = t4*16+l16 (d), keys = contiguous 8
    // positions (qtr&1)*32 + quad*8..+7 -> one b128 per t4.
    int voff[4];
    #pragma unroll
    for (int t4 = 0; t4 < 4; t4++) {
        const int row = t4 * 16 + l16;
        voff[t4] = row * 64 + (((((qtr & 1) * 4) + quad) ^ (row & 7)) * 8);
    }
    // true-token base for masking: r*128 + kmc2 + s + r4*16
    const int kmc2 = (qtr >> 1) * 64 + (qtr & 1) * 8 + quad * 2;

    // staging: waves 0-7 stage K (both 64-tiles), waves 8-15 stage V.
    const int  tv  = tid & 511;
    const int  rr  = tv >> 3;
    const int  ccK = (tv & 7) ^ ((((rr >> 4) & 3) << 1) | ((rr >> 1) & 1));
    const int  ccV = (tv & 7) ^ (rr & 7);
    const bool isK = (tid < 512);
    const int  dsto = (w & 7) * 512;
    const ushort_t* kse = kbase + (size_t)rr * D3 + ccK * 8;
    const ushort_t* vse = vbase + (size_t)rr * Lq + ccV * 8;

    for (int sel = 0; sel < 2; sel++) {
        const int c      = sel ? (31 - p) : p;
        const int qc     = c * 128;
        const int rounds = c + 1;
        const int qrow0  = qc + sub * 32;

        short8 qf[2][2];
        #pragma unroll
        for (int m = 0; m < 2; m++) {
            const ushort_t* qr = qkv + (size_t)(qrow0 + m * 16 + l16) * D3 + h * HD;
            qf[m][0] = *(const short8*)(qr + quad * 8);
            qf[m][1] = *(const short8*)(qr + 32 + quad * 8);
        }

        f32x4 o[2][4] = {};
        float sacc[2] = { 0.f, 0.f };

        const ushort_t* kp = kse;
        const ushort_t* vp = vse;

        auto stage = [&](int b) {
            if (isK) {
                gl2lds16(kp,           &sm.kv.K[0][b][dsto]);
                gl2lds16(kp + 64 * D3, &sm.kv.K[1][b][dsto]);
            } else {
                gl2lds16(vp,           &sm.kv.V[0][b][dsto]);
                gl2lds16(vp + 64,      &sm.kv.V[1][b][dsto]);
            }
            kp += (size_t)128 * D3;
            vp += 128;
        };

        stage(0);

        for (int r = 0; r < rounds; r++) {
            const int buf = r & 1;
            __syncthreads();
            if (r + 1 < rounds) stage(buf ^ 1);

            const ushort_t* Kb = &sm.kv.K[qtr >> 1][buf][0];
            const ushort_t* Vb = &sm.kv.V[qtr >> 1][buf][0];
            const bool domask = (r == rounds - 1);

            // hoist all fragment loads: PV becomes a pure-register cluster
            short8 kf[2][2];
            #pragma unroll
            for (int s = 0; s < 2; s++)
                #pragma unroll
                for (int kh = 0; kh < 2; kh++)
                    kf[s][kh] = *(const short8*)&Kb[koff[s][kh]];
            short8 vf[4];
            #pragma unroll
            for (int t4 = 0; t4 < 4; t4++)
                vf[t4] = *(const short8*)&Vb[voff[t4]];

            // S^T = K * Q^T (position-indexed rows), all 8 MFMAs batched
            f32x4 st[2][2];
            #pragma unroll
            for (int m = 0; m < 2; m++)
                #pragma unroll
                for (int s = 0; s < 2; s++) {
                    f32x4 t = {};
                    t = MFMA16(kf[s][0], qf[m][0], t);
                    t = MFMA16(kf[s][1], qf[m][1], t);
                    st[m][s] = t;
                }

            // exp2 + pack in-register; pP[m] = K=32 PV B-fragment directly
            short8 pP[2];
            #pragma unroll
            for (int m = 0; m < 2; m++) {
                const int qg = qrow0 + m * 16 + l16;
                union { unsigned int u[4]; short8 s8; } pb;
                #pragma unroll
                for (int s = 0; s < 2; s++) {
                    float e[4];
                    #pragma unroll
                    for (int r4 = 0; r4 < 4; r4++) {
                        float v = st[m][s][r4];
                        if (domask && (r * 128 + kmc2 + s + r4 * 16 > qg))
                            v = NEG_INF;
                        e[r4] = __builtin_amdgcn_exp2f(v);
                    }
                    sacc[m] += (e[0] + e[1]) + (e[2] + e[3]);
                    pb.u[s * 2]     = cvtpk(e[0], e[1]);
                    pb.u[s * 2 + 1] = cvtpk(e[2], e[3]);
                }
                pP[m] = pb.s8;
            }

            // PV: O^T[d][q] += V^T-frag * P^T-frag (16x16x32, 8 MFMAs)
            #pragma unroll
            for (int t4 = 0; t4 < 4; t4++) {
                o[0][t4] = MFMA16(vf[t4], pP[0], o[0][t4]);
                o[1][t4] = MFMA16(vf[t4], pP[1], o[1][t4]);
            }
        }

        // reduce sacc across quads (keys of this quarter fully summed)
        #pragma unroll
        for (int m = 0; m < 2; m++) {
            sacc[m] += __shfl_xor(sacc[m], 16);
            sacc[m] += __shfl_xor(sacc[m], 32);
        }

        // 4-way merge through Ml (aliases K/V LDS; rounds done, barriers
        // separate all uses).
        __syncthreads();
        if (qtr != 0) {
            float* dst = sm.Ml + (size_t)((qtr - 1) * 256 + sub * 64 + lane) * 35;
            #pragma unroll
            for (int m = 0; m < 2; m++)
                #pragma unroll
                for (int t4 = 0; t4 < 4; t4++)
                    *(f32x4*)(dst + (m * 4 + t4) * 4) = o[m][t4];
            dst[32] = sacc[0];
            dst[33] = sacc[1];
        }
        __syncthreads();
        if (qtr == 0) {
            #pragma unroll
            for (int j = 0; j < 3; j++) {
                const float* src = sm.Ml + (size_t)(j * 256 + sub * 64 + lane) * 35;
                #pragma unroll
                for (int m = 0; m < 2; m++)
                    #pragma unroll
                    for (int t4 = 0; t4 < 4; t4++)
                        o[m][t4] += *(const f32x4*)(src + (m * 4 + t4) * 4);
                sacc[0] += src[32];
                sacc[1] += src[33];
            }
            #pragma unroll
            for (int m = 0; m < 2; m++) {
                const float inv = 1.0f / sacc[m];
                ushort_t* orow = O + (size_t)(qrow0 + m * 16 + l16) * Dm + h * HD;
                #pragma unroll
                for (int t4 = 0; t4 < 4; t4++) {
                    ushort_t pk[4];
                    #pragma unroll
                    for (int r4 = 0; r4 < 4; r4++)
                        pk[r4] = f2bf(o[m][t4][r4] * inv);
                    *(uint2*)(orow + t4 * 16 + quad * 4) = *(const uint2*)pk;
                }
            }
        }
        __syncthreads();
    }
}

// ---------------- proj GEMM: 128x64 tiles, BK=64, XCD-swizzled ----------------
__global__ void __launch_bounds__(256, 2)
gemm_proj(const ushort_t* __restrict__ A, const ushort_t* __restrict__ Bt,
          const float* __restrict__ bias, float* __restrict__ C) {
    __shared__ alignas(16) ushort_t Alds[2][128 * 32];
    __shared__ alignas(16) ushort_t Blds[2][64 * 32];
    const int tid  = threadIdx.x;
    const int lane = tid & 63;
    const int w    = tid >> 6;
    const int quad = lane >> 4;
    const int l16  = lane & 15;
    // chunked XCD swizzle: 512 blocks, 64 consecutive per XCD.
    const int lin0 = blockIdx.y * 32 + blockIdx.x;
    const int lin  = (lin0 & 7) * 64 + (lin0 >> 3);
    const int mbase = (lin & 31) * 128;
    const int nbase = (lin >> 5) * 64;
    const int moff  = (w >> 1) * 64;
    const int noff  = (w & 1) * 32;
    const int K = Dm, N = Dm;

    f32x4 acc[4][2] = {};

    for (int kb = 0; kb < K; kb += 64) {
        __syncthreads();
        #pragma unroll
        for (int c = 0; c < 4; c++) {
            const int id    = c * 256 + w * 64 + lane;
            const int plane = id >> 9;
            const int rem   = id & 511;
            const int row   = rem >> 2, col = (rem & 3) * 8;
            gl2lds16(&A[(size_t)(mbase + row) * K + kb + plane * 32 + col],
                     &Alds[plane][(size_t)((c & 1) * 256 + w * 64) * 8]);
        }
        #pragma unroll
        for (int c = 0; c < 2; c++) {
            const int id    = c * 256 + w * 64 + lane;
            const int plane = id >> 8;
            const int rem   = id & 255;
            const int row   = rem >> 2, col = (rem & 3) * 8;
            gl2lds16(&Bt[(size_t)(nbase + row) * K + kb + plane * 32 + col],
                     &Blds[plane][(size_t)(w * 64) * 8]);
        }
        __syncthreads();
        #pragma unroll
        for (int kk = 0; kk < 2; kk++) {
            short8 a[4], b[2];
            #pragma unroll
            for (int m = 0; m < 4; m++)
                a[m] = *(const short8*)&Alds[kk][(moff + m * 16 + l16) * 32 + quad * 8];
            #pragma unroll
            for (int n = 0; n < 2; n++)
                b[n] = *(const short8*)&Blds[kk][(noff + n * 16 + l16) * 32 + quad * 8];
            #pragma unroll
            for (int m = 0; m < 4; m++)
                #pragma unroll
                for (int n = 0; n < 2; n++)
                    acc[m][n] = MFMA16(a[m], b[n], acc[m][n]);
        }
    }

    #pragma unroll
    for (int m = 0; m < 4; m++)
        #pragma unroll
        for (int n = 0; n < 2; n++)
            #pragma unroll
            for (int r = 0; r < 4; r++) {
                int row = mbase + moff + m * 16 + quad * 4 + r;
                int col = nbase + noff + n * 16 + l16;
                C[(size_t)row * N + col] = acc[m][n][r] + bias[col];
            }
}

// ---------------- launch ----------------
extern "C" void kernel_launch(void* const* d_in, const int* in_sizes, int n_in,
                              void* d_out, int out_size, void* d_ws, size_t ws_size,
                              hipStream_t stream) {
    const float* X     = (const float*)d_in[0];
    const float* Wqkv  = (const float*)d_in[1];
    const float* bqkv  = (const float*)d_in[2];
    const float* Wproj = (const float*)d_in[3];
    const float* bproj = (const float*)d_in[4];
    float* out = (float*)d_out;

    ushort_t* ws     = (ushort_t*)d_ws;
    ushort_t* Xb     = ws;                               // 4096x1024
    ushort_t* WqkvT  = Xb + (size_t)Lq * Dm;             // 3072x1024
    ushort_t* WprojT = WqkvT + (size_t)D3 * Dm;          // 1024x1024
    ushort_t* qkvB   = WprojT + (size_t)Dm * Dm;         // 4096x3072 (Q,K used)
    ushort_t* VtB    = qkvB + (size_t)Lq * D3;           // 16x64x4096
    ushort_t* Ob     = VtB + (size_t)NH * HD * Lq;       // 4096x1024

    prep<<<dim3(8192), 256, 0, stream>>>(X, Wqkv, Wproj, Xb, WqkvT, WprojT);

    gemm_qkv<<<dim3(Lq / 128, D3 / 128), 256, 0, stream>>>(
        Xb, WqkvT, bqkv, qkvB, VtB);

    attn_fwd<<<dim3(256), 1024, 0, stream>>>(qkvB, VtB, Ob);

    gemm_proj<<<dim3(Lq / 128, Dm / 64), 256, 0, stream>>>(
        Ob, WprojT, bproj, out);
}